// Round 1
// baseline (243.031 us; speedup 1.0000x reference)
//
#include <hip/hip_runtime.h>
#include <math.h>

#define KSZ 5
#define TS 16                 // output tile edge
#define HALO 3                // 1 (conv3x3) + 2 (5x5 var/patch)
#define FW (TS + 2*HALO)      // 22: staged flow tile edge
#define CW (TS + 2)           // 18: consistency tile edge (tile + conv halo 1)

__global__ __launch_bounds__(256)
void refine_kernel(const float* __restrict__ flow,
                   const float* __restrict__ w1, const float* __restrict__ b1,
                   const float* __restrict__ w2, const float* __restrict__ b2,
                   float* __restrict__ out, int H, int W)
{
    __shared__ float sf[2][FW][FW + 1];   // +1 pad vs bank conflicts
    __shared__ float sc[CW][CW + 1];

    const int tid = threadIdx.x;
    const int x0 = blockIdx.x * TS;
    const int y0 = blockIdx.y * TS;
    const int b  = blockIdx.z;

    // ---- stage flow tile + halo (zero-padded outside image) ----
    for (int c = 0; c < 2; ++c) {
        const float* src = flow + ((size_t)(b * 2 + c) * H) * W;
        for (int i = tid; i < FW * FW; i += 256) {
            int ly = i / FW, lx = i % FW;
            int gy = y0 - HALO + ly, gx = x0 - HALO + lx;
            float v = 0.f;
            if (gy >= 0 && gy < H && gx >= 0 && gx < W)
                v = src[(size_t)gy * W + gx];
            sf[c][ly][lx] = v;
        }
    }
    __syncthreads();

    // ---- consistency for tile + halo-1 ----
    // cons coord p -> global (y0-1+p, x0-1+p'); 5x5 window -> sf rows p..p+4
    for (int i = tid; i < CW * CW; i += 256) {
        int py = i / CW, px = i % CW;
        int gy = y0 - 1 + py, gx = x0 - 1 + px;
        float cons = 0.f;  // conv zero-padding: guidance outside image is 0
        if (gy >= 0 && gy < H && gx >= 0 && gx < W) {
            float v2[2];
            #pragma unroll
            for (int c = 0; c < 2; ++c) {
                float s = 0.f, s2 = 0.f;
                #pragma unroll
                for (int dy = 0; dy < KSZ; ++dy)
                    #pragma unroll
                    for (int dx = 0; dx < KSZ; ++dx) {
                        float v = sf[c][py + dy][px + dx];
                        s += v; s2 += v * v;
                    }
                // unbiased variance (ddof=1): (E[x^2]*25 - s^2/25)/24
                v2[c] = (s2 - s * s * (1.f / 25.f)) * (1.f / 24.f);
            }
            cons = __expf(-sqrtf(v2[0] * v2[0] + v2[1] * v2[1]));
        }
        sc[py][px] = cons;
    }
    __syncthreads();

    // ---- per-pixel fused conv3x3 -> relu -> conv1x1 -> patch dot ----
    const int ty = tid / TS, tx = tid % TS;

    // guidance 3x3 windows: g[c*9 + ky*3 + kx]
    float g[27];
    #pragma unroll
    for (int ky = 0; ky < 3; ++ky)
        #pragma unroll
        for (int kx = 0; kx < 3; ++kx) {
            g[0 * 9 + ky * 3 + kx] = sf[0][ty + 2 + ky][tx + 2 + kx];
            g[1 * 9 + ky * 3 + kx] = sf[1][ty + 2 + ky][tx + 2 + kx];
            g[2 * 9 + ky * 3 + kx] = sc[ty + ky][tx + kx];
        }

    // h = relu(conv3x3(guidance)); w1 is OIHW [32][3][3][3]
    float h[32];
    #pragma unroll
    for (int o = 0; o < 32; ++o) {
        float acc = b1[o];
        #pragma unroll
        for (int t = 0; t < 27; ++t)
            acc = fmaf(w1[o * 27 + t], g[t], acc);
        h[o] = fmaxf(acc, 0.f);
    }

    // kernels = conv1x1(h) [50 ch: c*25 + j], dot with 5x5 patches
    float r0 = 0.f, r1 = 0.f;
    #pragma unroll
    for (int j = 0; j < 25; ++j) {
        float k0 = b2[j], k1 = b2[25 + j];
        #pragma unroll
        for (int o = 0; o < 32; ++o) {
            k0 = fmaf(w2[j * 32 + o],        h[o], k0);
            k1 = fmaf(w2[(25 + j) * 32 + o], h[o], k1);
        }
        int dy = j / 5, dx = j % 5;
        r0 = fmaf(k0, sf[0][ty + 1 + dy][tx + 1 + dx], r0);
        r1 = fmaf(k1, sf[1][ty + 1 + dy][tx + 1 + dx], r1);
    }

    const int y = y0 + ty, x = x0 + tx;
    out[((size_t)(b * 2 + 0) * H + y) * W + x] = r0;
    out[((size_t)(b * 2 + 1) * H + y) * W + x] = r1;
}

extern "C" void kernel_launch(void* const* d_in, const int* in_sizes, int n_in,
                              void* d_out, int out_size, void* d_ws, size_t ws_size,
                              hipStream_t stream) {
    const float* flow = (const float*)d_in[0];
    const float* w1   = (const float*)d_in[1];
    const float* b1   = (const float*)d_in[2];
    const float* w2   = (const float*)d_in[3];
    const float* b2   = (const float*)d_in[4];
    float* out = (float*)d_out;

    const int H = 1024, W = 1024;
    const int B = in_sizes[0] / (2 * H * W);

    dim3 grid(W / TS, H / TS, B);
    refine_kernel<<<grid, dim3(256), 0, stream>>>(flow, w1, b1, w2, b2, out, H, W);
}

// Round 2
// 183.926 us; speedup vs baseline: 1.3213x; 1.3213x over previous
//
#include <hip/hip_runtime.h>
#include <math.h>

#define KSZ 5
#define TS 16                 // output tile edge (16x16 px = 256 threads)
#define HALO 3                // 1 (conv3x3) + 2 (5x5 var/patch)
#define FW (TS + 2*HALO)      // 22: staged flow tile edge
#define CW (TS + 2)           // 18: consistency tile edge

typedef __attribute__((ext_vector_type(8))) short short8_t;  // 8 bf16 (4 VGPRs)
typedef __attribute__((ext_vector_type(4))) float float4_t;

static __device__ __forceinline__ unsigned short f2bf(float f) {
    union { float f; unsigned int u; } v; v.f = f;
    unsigned int r = (v.u + 0x7FFFu + ((v.u >> 16) & 1u)) >> 16;  // RNE
    return (unsigned short)r;
}

__global__ __launch_bounds__(256)
void refine_kernel(const float* __restrict__ flow,
                   const float* __restrict__ w1, const float* __restrict__ b1,
                   const float* __restrict__ w2, const float* __restrict__ b2,
                   float* __restrict__ out, int H, int W)
{
    __shared__ float sf[2][FW][FW + 1];
    __shared__ float sc[CW][CW + 1];
    __shared__ __align__(16) unsigned short a1[256][32];  // guidance bf16; reused as h bf16
    __shared__ __align__(16) unsigned short wB[96 * 32];  // rows 0..31: W1, rows 32..95: W2(padded)
    __shared__ float biases[96];                          // 0..31: b1, 32..95: b2 padded

    const int tid = threadIdx.x;
    const int x0 = blockIdx.x * TS;
    const int y0 = blockIdx.y * TS;
    const int b  = blockIdx.z;

    // ---- phase 0: stage flow tile + halo; weights -> bf16 LDS ----
    for (int c = 0; c < 2; ++c) {
        const float* src = flow + ((size_t)(b * 2 + c) * H) * W;
        for (int i = tid; i < FW * FW; i += 256) {
            int ly = i / FW, lx = i % FW;
            int gy = y0 - HALO + ly, gx = x0 - HALO + lx;
            float v = 0.f;
            if (gy >= 0 && gy < H && gx >= 0 && gx < W) v = src[(size_t)gy * W + gx];
            sf[c][ly][lx] = v;
        }
    }
    for (int i = tid; i < 32 * 32; i += 256) {             // W1 [32 out][27 in] -> [32][32]
        int n = i >> 5, k = i & 31;
        wB[i] = f2bf((k < 27) ? w1[n * 27 + k] : 0.f);
    }
    for (int i = tid; i < 64 * 32; i += 256) {             // W2 [50 out][32 in] -> [64][32]
        int n = i >> 5, k = i & 31;
        wB[32 * 32 + i] = f2bf((n < 50) ? w2[n * 32 + k] : 0.f);
    }
    for (int i = tid; i < 96; i += 256) {
        float v;
        if (i < 32) v = b1[i];
        else { int j = i - 32; v = (j < 50) ? b2[j] : 0.f; }
        biases[i] = v;
    }
    __syncthreads();

    // ---- phase 1: consistency (ddof=1 variance over 5x5, both channels) ----
    for (int i = tid; i < CW * CW; i += 256) {
        int py = i / CW, px = i % CW;
        int gy = y0 - 1 + py, gx = x0 - 1 + px;
        float cons = 0.f;  // conv zero-padding: guidance outside image is 0
        if (gy >= 0 && gy < H && gx >= 0 && gx < W) {
            float v2[2];
            #pragma unroll
            for (int c = 0; c < 2; ++c) {
                float s = 0.f, s2 = 0.f;
                #pragma unroll
                for (int dy = 0; dy < KSZ; ++dy)
                    #pragma unroll
                    for (int dx = 0; dx < KSZ; ++dx) {
                        float v = sf[c][py + dy][px + dx];
                        s += v; s2 += v * v;
                    }
                v2[c] = (s2 - s * s * (1.f / 25.f)) * (1.f / 24.f);
            }
            cons = __expf(-sqrtf(v2[0] * v2[0] + v2[1] * v2[1]));
        }
        sc[py][px] = cons;
    }
    __syncthreads();

    // ---- phase 2: guidance bf16 -> a1[tid][0..31] (k = c*9+ky*3+kx, OIHW) ----
    {
        const int ty = tid >> 4, tx = tid & 15;
        unsigned short gv[32];
        #pragma unroll
        for (int ky = 0; ky < 3; ++ky)
            #pragma unroll
            for (int kx = 0; kx < 3; ++kx) {
                gv[0 * 9 + ky * 3 + kx] = f2bf(sf[0][ty + 2 + ky][tx + 2 + kx]);
                gv[1 * 9 + ky * 3 + kx] = f2bf(sf[1][ty + 2 + ky][tx + 2 + kx]);
                gv[2 * 9 + ky * 3 + kx] = f2bf(sc[ty + ky][tx + kx]);
            }
        #pragma unroll
        for (int k = 27; k < 32; ++k) gv[k] = 0;
        unsigned int* dst = (unsigned int*)&a1[tid][0];
        #pragma unroll
        for (int q = 0; q < 16; ++q)
            dst[q] = (unsigned int)gv[2 * q] | ((unsigned int)gv[2 * q + 1] << 16);
    }
    // no barrier needed: each wave only consumes its own 64 rows of a1

    const int lane = tid & 63;
    const int wave = tid >> 6;
    const int col  = lane & 15;     // A: m-row | B: n-row | C: column
    const int g4   = lane >> 4;     // A/B: k-chunk | C: row-group
    const int wbase = wave * 64;

    // hoisted B-frags (lane n = col, k chunk = g4*8) and biases
    short8_t w1f[2], w2f[4];
    #pragma unroll
    for (int nt = 0; nt < 2; ++nt)
        w1f[nt] = *(const short8_t*)&wB[(nt * 16 + col) * 32 + g4 * 8];
    #pragma unroll
    for (int nt = 0; nt < 4; ++nt)
        w2f[nt] = *(const short8_t*)&wB[(32 + nt * 16 + col) * 32 + g4 * 8];
    float cb1[2], cb2[4];
    cb1[0] = biases[col]; cb1[1] = biases[16 + col];
    #pragma unroll
    for (int nt = 0; nt < 4; ++nt) cb2[nt] = biases[32 + nt * 16 + col];

    // per-nt patch-tap metadata: ch = nt*16+col -> (c, dy, dx)
    int   sfoff[4];
    bool  valid[4], isc1[4];
    #pragma unroll
    for (int nt = 0; nt < 4; ++nt) {
        int ch = nt * 16 + col;
        valid[nt] = (ch < 50);
        int c = (ch >= 25) ? 1 : 0;
        int j = valid[nt] ? (ch - c * 25) : 0;
        if (!valid[nt]) c = 0;
        isc1[nt] = (c == 1);
        int dy = j / 5, dx = j % 5;
        sfoff[nt] = c * (FW * (FW + 1)) + (1 + dy) * (FW + 1) + (1 + dx);
    }
    const float* sfflat = &sf[0][0][0];

    #pragma unroll
    for (int mt = 0; mt < 4; ++mt) {
        const int mbase = wbase + mt * 16;
        // GEMM1: guidance -> h (bias in C-init, relu after)
        short8_t af = *(const short8_t*)&a1[mbase + col][g4 * 8];
        float4_t h0 = {cb1[0], cb1[0], cb1[0], cb1[0]};
        float4_t h1 = {cb1[1], cb1[1], cb1[1], cb1[1]};
        h0 = __builtin_amdgcn_mfma_f32_16x16x32_bf16(af, w1f[0], h0, 0, 0, 0);
        h1 = __builtin_amdgcn_mfma_f32_16x16x32_bf16(af, w1f[1], h1, 0, 0, 0);
        // relu + bf16, store back into a1 rows of this (already consumed) m-tile
        #pragma unroll
        for (int r = 0; r < 4; ++r) {
            int p = mbase + g4 * 4 + r;       // C row mapping
            a1[p][col]      = f2bf(fmaxf(h0[r], 0.f));
            a1[p][16 + col] = f2bf(fmaxf(h1[r], 0.f));
        }
        // GEMM2: h -> 50 kernel coeffs (padded to 64)
        short8_t hf = *(const short8_t*)&a1[mbase + col][g4 * 8];
        float4_t ka[4];
        #pragma unroll
        for (int nt = 0; nt < 4; ++nt) {
            ka[nt] = (float4_t){cb2[nt], cb2[nt], cb2[nt], cb2[nt]};
            ka[nt] = __builtin_amdgcn_mfma_f32_16x16x32_bf16(hf, w2f[nt], ka[nt], 0, 0, 0);
        }
        // patch dot in C-layout: lane's channel taps x its 4 pixels
        const int ty = wave * 4 + mt;         // image row of this m-tile
        float s0[4] = {0.f, 0.f, 0.f, 0.f}, s1[4] = {0.f, 0.f, 0.f, 0.f};
        #pragma unroll
        for (int nt = 0; nt < 4; ++nt) {
            #pragma unroll
            for (int r = 0; r < 4; ++r) {
                int tx = g4 * 4 + r;
                float pv = valid[nt] ? sfflat[sfoff[nt] + ty * (FW + 1) + tx] : 0.f;
                float prod = ka[nt][r] * pv;
                if (isc1[nt]) s1[r] += prod; else s0[r] += prod;
            }
        }
        // reduce over the 16 channel-lanes (xor 1,2,4,8 stays in group)
        #pragma unroll
        for (int r = 0; r < 4; ++r) {
            float v0 = s0[r], v1 = s1[r];
            #pragma unroll
            for (int m = 1; m < 16; m <<= 1) {
                v0 += __shfl_xor(v0, m);
                v1 += __shfl_xor(v1, m);
            }
            s0[r] = v0; s1[r] = v1;
        }
        if (col == 0) {
            float4_t o0 = {s0[0], s0[1], s0[2], s0[3]};
            float4_t o1 = {s1[0], s1[1], s1[2], s1[3]};
            int y = y0 + ty, x = x0 + g4 * 4;
            *(float4_t*)&out[((size_t)(b * 2 + 0) * H + y) * W + x] = o0;
            *(float4_t*)&out[((size_t)(b * 2 + 1) * H + y) * W + x] = o1;
        }
    }
}

extern "C" void kernel_launch(void* const* d_in, const int* in_sizes, int n_in,
                              void* d_out, int out_size, void* d_ws, size_t ws_size,
                              hipStream_t stream) {
    const float* flow = (const float*)d_in[0];
    const float* w1   = (const float*)d_in[1];
    const float* b1   = (const float*)d_in[2];
    const float* w2   = (const float*)d_in[3];
    const float* b2   = (const float*)d_in[4];
    float* out = (float*)d_out;

    const int H = 1024, W = 1024;
    const int B = in_sizes[0] / (2 * H * W);

    dim3 grid(W / TS, H / TS, B);
    refine_kernel<<<grid, dim3(256), 0, stream>>>(flow, w1, b1, w2, b2, out, H, W);
}

// Round 3
// 164.723 us; speedup vs baseline: 1.4754x; 1.1166x over previous
//
#include <hip/hip_runtime.h>
#include <math.h>

#define KSZ 5
#define TS 16
#define HALO 3
#define FW (TS + 2*HALO)      // 22
#define FWP (FW + 1)          // 23 (pad)
#define CW (TS + 2)           // 18
#define CWP (CW + 1)          // 19
#define SF_C (FW*FWP)         // 506 floats per flow channel
#define SC_BASE (2*SF_C)      // sc starts here in smf

typedef __attribute__((ext_vector_type(8))) short short8_t;  // 8 bf16
typedef __attribute__((ext_vector_type(4))) float float4_t;
typedef __attribute__((ext_vector_type(2))) unsigned int uint2_t;

static __device__ __forceinline__ unsigned short f2bf(float f) {
    union { float f; unsigned int u; } v; v.f = f;
    return (unsigned short)((v.u + 0x7FFFu + ((v.u >> 16) & 1u)) >> 16);  // RNE
}
static __device__ __forceinline__ unsigned int pack2(float a, float b) {
    return (unsigned int)f2bf(a) | ((unsigned int)f2bf(b) << 16);
}

__global__ __launch_bounds__(256)
void refine_kernel(const float* __restrict__ flow,
                   const float* __restrict__ w1, const float* __restrict__ b1,
                   const float* __restrict__ w2, const float* __restrict__ b2,
                   float* __restrict__ out, int H, int W)
{
    __shared__ float smf[SC_BASE + CW*CWP];               // sf[2][22][23] | sc[18][19]
    __shared__ __align__(16) unsigned short wB[96*32];    // W1 rows 0..31; W2' rows 32..95
    __shared__ __align__(16) float biases[96];            // b1 | b2' (group-padded)
    __shared__ __align__(16) unsigned short hb[4*16*32];  // per-wave h tile, 16B-chunk swizzled

    const int tid = threadIdx.x;
    const int x0 = blockIdx.x * TS;
    const int y0 = blockIdx.y * TS;
    const int b  = blockIdx.z;

    // ---- phase 0: stage flow (+halo, zero-padded); weights -> bf16 LDS ----
    for (int c = 0; c < 2; ++c) {
        const float* src = flow + ((size_t)(b*2+c) * H) * W;
        for (int i = tid; i < FW*FW; i += 256) {
            int ly = i / FW, lx = i - ly*FW;
            int gy = y0 - HALO + ly, gx = x0 - HALO + lx;
            float v = 0.f;
            if (gy >= 0 && gy < H && gx >= 0 && gx < W) v = src[(size_t)gy*W + gx];
            smf[c*SF_C + ly*FWP + lx] = v;
        }
    }
    for (int i = tid; i < 32*32; i += 256) {              // W1 [32 out][27->32 in]
        int n = i >> 5, k = i & 31;
        wB[i] = f2bf((k < 27) ? w1[n*27 + k] : 0.f);
    }
    // W2' row n: c = n>>5, j = n&31; valid j<25 -> w2[(c*25+j)*32+k], else 0
    for (int i = tid; i < 64*32; i += 256) {
        int n = i >> 5, k = i & 31;
        int c = n >> 5, j = n & 31;
        wB[32*32 + i] = f2bf((j < 25) ? w2[(c*25 + j)*32 + k] : 0.f);
    }
    for (int i = tid; i < 96; i += 256) {
        float v;
        if (i < 32) v = b1[i];
        else { int n = i - 32, c = n >> 5, j = n & 31; v = (j < 25) ? b2[c*25 + j] : 0.f; }
        biases[i] = v;
    }
    __syncthreads();

    // ---- phase 1: consistency sc (ddof=1 variance over 5x5, both channels) ----
    for (int i = tid; i < CW*CW; i += 256) {
        int py = i / CW, px = i - py*CW;
        int gy = y0 - 1 + py, gx = x0 - 1 + px;
        float cons = 0.f;  // conv zero-padding: guidance outside image is 0
        if (gy >= 0 && gy < H && gx >= 0 && gx < W) {
            float v2[2];
            #pragma unroll
            for (int c = 0; c < 2; ++c) {
                float s = 0.f, s2 = 0.f;
                #pragma unroll
                for (int dy = 0; dy < KSZ; ++dy)
                    #pragma unroll
                    for (int dx = 0; dx < KSZ; ++dx) {
                        float v = smf[c*SF_C + (py+dy)*FWP + (px+dx)];
                        s += v; s2 += v * v;
                    }
                v2[c] = (s2 - s * s * (1.f/25.f)) * (1.f/24.f);
            }
            cons = __expf(-sqrtf(v2[0]*v2[0] + v2[1]*v2[1]));
        }
        smf[SC_BASE + py*CWP + px] = cons;
    }
    __syncthreads();

    // ---- main: per-wave, A = weights, B = 16 pixels (one image row per mt) ----
    const int lane = tid & 63;
    const int wave = tid >> 6;
    const int col  = lane & 15;        // C col = pixel x-in-tile; A/B row index
    const int g4   = lane >> 4;        // k-chunk / C row-group
    const int key  = col >> 2;         // 16B-chunk swizzle key for hb

    // hoisted A-frags (weights) and bias C-inits
    short8_t w1A[2], w2A[4];
    #pragma unroll
    for (int nt = 0; nt < 2; ++nt)
        w1A[nt] = *(const short8_t*)&wB[(nt*16 + col)*32 + g4*8];
    #pragma unroll
    for (int nt = 0; nt < 4; ++nt)
        w2A[nt] = *(const short8_t*)&wB[(32 + nt*16 + col)*32 + g4*8];
    float4_t cb1[2], cb2[4];
    #pragma unroll
    for (int nt = 0; nt < 2; ++nt) cb1[nt] = *(const float4_t*)&biases[nt*16 + g4*4];
    #pragma unroll
    for (int nt = 0; nt < 4; ++nt) cb2[nt] = *(const float4_t*)&biases[32 + nt*16 + g4*4];

    // guidance tap metadata: this lane supplies B[n=col][k=g4*8+j]
    int goff[8], gpitch[8]; bool gval[8];
    #pragma unroll
    for (int j = 0; j < 8; ++j) {
        int ch = g4*8 + j;
        bool v = (ch < 27);
        int chc = v ? ch : 0;
        int c = chc / 9, rem = chc - 9*c;
        int ky = rem / 3, kx = rem - 3*ky;
        if (c < 2) { goff[j] = c*SF_C + (2+ky)*FWP + (2+kx) + col; gpitch[j] = FWP; }
        else       { goff[j] = SC_BASE + ky*CWP + kx + col;        gpitch[j] = CWP; }
        gval[j] = v;
    }

    // patch tap metadata: ka channel (nt,r) -> c = nt>>1, j = (nt&1)*16+g4*4+r
    int poff[16];
    #pragma unroll
    for (int i = 0; i < 16; ++i) {
        int nt = i >> 2, r = i & 3;
        int c = nt >> 1;
        int j = (nt & 1)*16 + g4*4 + r;
        j = (j > 24) ? 24 : j;               // clamp; ka==0 there anyway
        int dy = j / 5, dx = j - 5*dy;
        poff[i] = c*SF_C + (1+dy)*FWP + (1+dx) + col;
    }

    const int hrow = (wave*16 + col) * 64;   // byte base of this lane's hb row

    #pragma unroll
    for (int mt = 0; mt < 4; ++mt) {
        const int ty = wave*4 + mt;          // image row within tile

        // build guidance B-frag in-register
        unsigned int gd[4];
        #pragma unroll
        for (int t = 0; t < 4; ++t) {
            float va = gval[2*t]   ? smf[goff[2*t]   + ty*gpitch[2*t]]   : 0.f;
            float vb = gval[2*t+1] ? smf[goff[2*t+1] + ty*gpitch[2*t+1]] : 0.f;
            gd[t] = pack2(va, vb);
        }
        union { unsigned int u[4]; short8_t s; } gu;
        gu.u[0] = gd[0]; gu.u[1] = gd[1]; gu.u[2] = gd[2]; gu.u[3] = gd[3];
        short8_t gB = gu.s;

        // GEMM1: h = relu(W1 . g + b1)  (C: row=out-ch, col=pixel)
        float4_t h0 = __builtin_amdgcn_mfma_f32_16x16x32_bf16(w1A[0], gB, cb1[0], 0, 0, 0);
        float4_t h1 = __builtin_amdgcn_mfma_f32_16x16x32_bf16(w1A[1], gB, cb1[1], 0, 0, 0);

        // pack 4 consecutive channels -> one b64 write (swizzled 16B chunks)
        #pragma unroll
        for (int nt = 0; nt < 2; ++nt) {
            float4_t hh = nt ? h1 : h0;
            uint2_t d;
            d.x = pack2(fmaxf(hh[0], 0.f), fmaxf(hh[1], 0.f));
            d.y = pack2(fmaxf(hh[2], 0.f), fmaxf(hh[3], 0.f));
            int chunk = nt*2 + (g4 >> 1);
            *(uint2_t*)((char*)hb + hrow + ((chunk ^ key) << 4) + ((g4 & 1) << 3)) = d;
        }
        // read h B-frag (this lane's pixel, its k-chunk)
        short8_t hf = *(const short8_t*)((char*)hb + hrow + ((g4 ^ key) << 4));

        // GEMM2: ka = W2' . h + b2'   (row=kernel-channel, col=pixel)
        float4_t ka[4];
        #pragma unroll
        for (int nt = 0; nt < 4; ++nt)
            ka[nt] = __builtin_amdgcn_mfma_f32_16x16x32_bf16(w2A[nt], hf, cb2[nt], 0, 0, 0);

        // patch dot: lane's 16 channels x its pixel's taps; c compile-time per nt
        const int rowadd = ty * FWP;
        float s0 = 0.f, s1 = 0.f;
        #pragma unroll
        for (int i = 0; i < 16; ++i) {
            float pv = smf[poff[i] + rowadd];
            float prod = ka[i >> 2][i & 3] * pv;
            if ((i >> 3) == 0) s0 += prod; else s1 += prod;
        }
        // sum the 4 g4-groups (channels) per pixel
        s0 += __shfl_xor(s0, 16); s0 += __shfl_xor(s0, 32);
        s1 += __shfl_xor(s1, 16); s1 += __shfl_xor(s1, 32);

        if (g4 == 0) {
            int y = y0 + ty, x = x0 + col;
            out[((size_t)(b*2 + 0) * H + y) * W + x] = s0;
            out[((size_t)(b*2 + 1) * H + y) * W + x] = s1;
        }
    }
}

extern "C" void kernel_launch(void* const* d_in, const int* in_sizes, int n_in,
                              void* d_out, int out_size, void* d_ws, size_t ws_size,
                              hipStream_t stream) {
    const float* flow = (const float*)d_in[0];
    const float* w1   = (const float*)d_in[1];
    const float* b1   = (const float*)d_in[2];
    const float* w2   = (const float*)d_in[3];
    const float* b2   = (const float*)d_in[4];
    float* out = (float*)d_out;

    const int H = 1024, W = 1024;
    const int B = in_sizes[0] / (2 * H * W);

    dim3 grid(W / TS, H / TS, B);
    refine_kernel<<<grid, dim3(256), 0, stream>>>(flow, w1, b1, w2, b2, out, H, W);
}

// Round 4
// 155.628 us; speedup vs baseline: 1.5616x; 1.0584x over previous
//
#include <hip/hip_runtime.h>
#include <math.h>

#define KSZ 5
#define TS 16
#define HALO 3
#define FW (TS + 2*HALO)      // 22
#define FWP (FW + 1)          // 23 (pad)
#define CW (TS + 2)           // 18
#define CWP (CW + 1)          // 19
#define SF_C (FW*FWP)         // 506 floats per flow channel
#define SC_BASE (2*SF_C)      // sc starts here in smf

typedef __attribute__((ext_vector_type(8))) short short8_t;  // 8 bf16
typedef __attribute__((ext_vector_type(4))) float float4_t;
typedef __attribute__((ext_vector_type(2))) unsigned int uint2_t;

static __device__ __forceinline__ unsigned short f2bf(float f) {
    union { float f; unsigned int u; } v; v.f = f;
    return (unsigned short)((v.u + 0x7FFFu + ((v.u >> 16) & 1u)) >> 16);  // RNE
}

static __device__ __forceinline__ unsigned int pk2(float a, float b) {
#if __has_builtin(__builtin_amdgcn_cvt_pk_bf16_f32)
    auto r = __builtin_amdgcn_cvt_pk_bf16_f32(a, b);
    union { decltype(r) v; unsigned int u; } cv; cv.v = r; return cv.u;
#else
    return (unsigned int)f2bf(a) | ((unsigned int)f2bf(b) << 16);
#endif
}

// ---- one-block pack kernel: weights/biases -> MFMA-fragment order in ws ----
__global__ __launch_bounds__(256)
void pack_kernel(const float* __restrict__ w1, const float* __restrict__ b1,
                 const float* __restrict__ w2, const float* __restrict__ b2,
                 unsigned short* __restrict__ wp, float* __restrict__ bp)
{
    const int tid = threadIdx.x;
    // weight frags: f 0..1 = W1 nt, f 2..5 = W2' nt.  entry: wp[(f*64+l)*8 + j]
    for (int i = tid; i < 6*64*8; i += 256) {
        int f = i >> 9, l = (i >> 3) & 63, j = i & 7;
        int col = l & 15, g4 = l >> 4, k = g4*8 + j;
        float v;
        if (f < 2) { int row = f*16 + col; v = (k < 27) ? w1[row*27 + k] : 0.f; }
        else { int n = (f-2)*16 + col; int c = n >> 5, jj = n & 31;
               v = (jj < 25) ? w2[(c*25 + jj)*32 + k] : 0.f; }
        wp[i] = f2bf(v);
    }
    // bias frags: f 0..1 = b1 nt, f 2..5 = b2' nt.  entry: bp[(f*64+l)*4 + r]
    for (int i = tid; i < 6*64*4; i += 256) {
        int f = i >> 8, l = (i >> 2) & 63, r = i & 3, g4 = l >> 4;
        int base = (f < 2) ? f*16 : (f-2)*16;
        int n = base + g4*4 + r;
        float v;
        if (f < 2) v = b1[n];
        else { int c = n >> 5, jj = n & 31; v = (jj < 25) ? b2[c*25 + jj] : 0.f; }
        bp[i] = v;
    }
}

__global__ __launch_bounds__(256)
void refine_kernel(const float* __restrict__ flow,
                   const unsigned short* __restrict__ wp,
                   const float* __restrict__ bp,
                   float* __restrict__ out, int H, int W)
{
    __shared__ float smf[SC_BASE + CW*CWP];       // sf[2][22][23] | sc[18][19]
    __shared__ __align__(16) char dyn[6400];      // rs[22][18] float4 (phase1) / hb (main)

    const int tid = threadIdx.x;
    const int x0 = blockIdx.x * TS;
    const int y0 = blockIdx.y * TS;
    const int b  = blockIdx.z;

    const int lane = tid & 63;
    const int wave = tid >> 6;
    const int col  = lane & 15;        // C col = pixel x-in-tile; A row index
    const int g4   = lane >> 4;        // k-chunk / C row-group
    const int key  = col >> 2;         // 16B-chunk swizzle key for hb

    // ---- fragment loads from pre-packed ws (L2-resident, coalesced b128) ----
    short8_t w1A[2], w2A[4];
    float4_t cb1[2], cb2[4];
    #pragma unroll
    for (int nt = 0; nt < 2; ++nt) {
        w1A[nt] = *(const short8_t*)&wp[(nt*64 + lane)*8];
        cb1[nt] = *(const float4_t*)&bp[(nt*64 + lane)*4];
    }
    #pragma unroll
    for (int nt = 0; nt < 4; ++nt) {
        w2A[nt] = *(const short8_t*)&wp[((2+nt)*64 + lane)*8];
        cb2[nt] = *(const float4_t*)&bp[((2+nt)*64 + lane)*4];
    }

    // ---- phase 0: stage flow tile + halo (zero-padded outside image) ----
    for (int c = 0; c < 2; ++c) {
        const float* src = flow + ((size_t)(b*2+c) * H) * W;
        for (int i = tid; i < FW*FW; i += 256) {
            int ly = i / FW, lx = i - ly*FW;
            int gy = y0 - HALO + ly, gx = x0 - HALO + lx;
            float v = 0.f;
            if (gy >= 0 && gy < H && gx >= 0 && gx < W) v = src[(size_t)gy*W + gx];
            smf[c*SF_C + ly*FWP + lx] = v;
        }
    }
    __syncthreads();

    // ---- phase 1a: horizontal 5-tap sums (s, sum v^2) both channels ----
    {
        float4_t* rs = (float4_t*)dyn;            // [FW][CW]
        for (int i = tid; i < FW*CW; i += 256) {
            int y = i / CW, x = i - y*CW;
            const float* r0 = &smf[y*FWP + x];
            const float* r1 = &smf[SF_C + y*FWP + x];
            float s0 = 0.f, q0 = 0.f, s1 = 0.f, q1 = 0.f;
            #pragma unroll
            for (int dx = 0; dx < KSZ; ++dx) {
                float a = r0[dx]; s0 += a; q0 = fmaf(a, a, q0);
                float c = r1[dx]; s1 += c; q1 = fmaf(c, c, q1);
            }
            rs[i] = (float4_t){s0, q0, s1, q1};
        }
    }
    __syncthreads();

    // ---- phase 1b: vertical 5-row sum -> variance (ddof=1) -> consistency ----
    for (int i = tid; i < CW*CW; i += 256) {
        int py = i / CW, px = i - py*CW;
        int gy = y0 - 1 + py, gx = x0 - 1 + px;
        float cons = 0.f;  // conv zero-padding: guidance outside image is 0
        if (gy >= 0 && gy < H && gx >= 0 && gx < W) {
            const float4_t* rp = (const float4_t*)dyn + py*CW + px;
            float4_t acc = rp[0];
            #pragma unroll
            for (int dy = 1; dy < KSZ; ++dy) acc += rp[dy*CW];
            float v0 = (acc.y - acc.x*acc.x*(1.f/25.f)) * (1.f/24.f);
            float v1 = (acc.w - acc.z*acc.z*(1.f/25.f)) * (1.f/24.f);
            cons = __expf(-sqrtf(v0*v0 + v1*v1));
        }
        smf[SC_BASE + py*CWP + px] = cons;
    }
    __syncthreads();   // sc + rs consumers/producers separated; dyn now reused as hb

    // ---- main: per-wave, A = weights, B = 16 pixels (one image row per mt) ----
    unsigned short* hb = (unsigned short*)dyn;

    // guidance tap metadata (incremental offsets; init at ty = wave*4)
    int goff[8], gpitch[8]; bool gval[8];
    #pragma unroll
    for (int j = 0; j < 8; ++j) {
        int ch = g4*8 + j;
        bool v = (ch < 27);
        int chc = v ? ch : 0;
        int c = chc / 9, rem = chc - 9*c;
        int ky = rem / 3, kx = rem - 3*ky;
        if (c < 2) { goff[j] = c*SF_C + (2+ky)*FWP + (2+kx) + col; gpitch[j] = FWP; }
        else       { goff[j] = SC_BASE + ky*CWP + kx + col;        gpitch[j] = CWP; }
        goff[j] += wave*4 * gpitch[j];
        gval[j] = v;
    }

    // patch tap metadata: ka channel (nt,r) -> c = nt>>1, j = (nt&1)*16+g4*4+r
    int poff[16];
    #pragma unroll
    for (int i = 0; i < 16; ++i) {
        int nt = i >> 2, r = i & 3;
        int c = nt >> 1;
        int j = (nt & 1)*16 + g4*4 + r;
        j = (j > 24) ? 24 : j;               // clamp; ka==0 there anyway
        int dy = j / 5, dx = j - 5*dy;
        poff[i] = c*SF_C + (1+dy)*FWP + (1+dx) + col + wave*4*FWP;
    }

    const int hrow = (wave*16 + col) * 64;   // byte base of this lane's hb row

    #pragma unroll
    for (int mt = 0; mt < 4; ++mt) {
        const int ty = wave*4 + mt;          // image row within tile

        // build guidance B-frag in-register
        unsigned int gd[4];
        #pragma unroll
        for (int t = 0; t < 4; ++t) {
            float va = gval[2*t]   ? smf[goff[2*t]]   : 0.f;
            float vb = gval[2*t+1] ? smf[goff[2*t+1]] : 0.f;
            gd[t] = pk2(va, vb);
        }
        #pragma unroll
        for (int j = 0; j < 8; ++j) goff[j] += gpitch[j];
        union { unsigned int u[4]; short8_t s; } gu;
        gu.u[0] = gd[0]; gu.u[1] = gd[1]; gu.u[2] = gd[2]; gu.u[3] = gd[3];
        short8_t gB = gu.s;

        // GEMM1: h = relu(W1 . g + b1)  (C: row=out-ch, col=pixel)
        float4_t h0 = __builtin_amdgcn_mfma_f32_16x16x32_bf16(w1A[0], gB, cb1[0], 0, 0, 0);
        float4_t h1 = __builtin_amdgcn_mfma_f32_16x16x32_bf16(w1A[1], gB, cb1[1], 0, 0, 0);

        // pack 4 consecutive channels -> one b64 write (swizzled 16B chunks)
        #pragma unroll
        for (int nt = 0; nt < 2; ++nt) {
            float4_t hh = nt ? h1 : h0;
            uint2_t d;
            d.x = pk2(fmaxf(hh[0], 0.f), fmaxf(hh[1], 0.f));
            d.y = pk2(fmaxf(hh[2], 0.f), fmaxf(hh[3], 0.f));
            int chunk = nt*2 + (g4 >> 1);
            *(uint2_t*)((char*)hb + hrow + ((chunk ^ key) << 4) + ((g4 & 1) << 3)) = d;
        }
        // read h B-frag (this lane's pixel, its k-chunk)
        short8_t hf = *(const short8_t*)((char*)hb + hrow + ((g4 ^ key) << 4));

        // GEMM2: ka = W2' . h + b2'   (row=kernel-channel, col=pixel)
        float4_t ka[4];
        #pragma unroll
        for (int nt = 0; nt < 4; ++nt)
            ka[nt] = __builtin_amdgcn_mfma_f32_16x16x32_bf16(w2A[nt], hf, cb2[nt], 0, 0, 0);

        // patch dot: lane's 16 channels x its pixel's taps; c compile-time per nt
        float s0 = 0.f, s1 = 0.f;
        #pragma unroll
        for (int i = 0; i < 16; ++i) {
            float pv = smf[poff[i]];
            float prod = ka[i >> 2][i & 3] * pv;
            if ((i >> 3) == 0) s0 += prod; else s1 += prod;
        }
        #pragma unroll
        for (int i = 0; i < 16; ++i) poff[i] += FWP;

        // sum the 4 g4-groups (channels) per pixel
        s0 += __shfl_xor(s0, 16); s0 += __shfl_xor(s0, 32);
        s1 += __shfl_xor(s1, 16); s1 += __shfl_xor(s1, 32);

        if (g4 == 0) {
            int y = y0 + ty, x = x0 + col;
            out[((size_t)(b*2 + 0) * H + y) * W + x] = s0;
            out[((size_t)(b*2 + 1) * H + y) * W + x] = s1;
        }
    }
}

extern "C" void kernel_launch(void* const* d_in, const int* in_sizes, int n_in,
                              void* d_out, int out_size, void* d_ws, size_t ws_size,
                              hipStream_t stream) {
    const float* flow = (const float*)d_in[0];
    const float* w1   = (const float*)d_in[1];
    const float* b1   = (const float*)d_in[2];
    const float* w2   = (const float*)d_in[3];
    const float* b2   = (const float*)d_in[4];
    float* out = (float*)d_out;

    unsigned short* wp = (unsigned short*)d_ws;                 // 6*64*8 ushort = 6 KB
    float* bp = (float*)((char*)d_ws + 8192);                   // 6*64*4 float = 6 KB

    const int H = 1024, W = 1024;
    const int B = in_sizes[0] / (2 * H * W);

    pack_kernel<<<1, 256, 0, stream>>>(w1, b1, w2, b2, wp, bp);
    dim3 grid(W / TS, H / TS, B);
    refine_kernel<<<grid, dim3(256), 0, stream>>>(flow, wp, bp, out, H, W);
}

// Round 5
// 130.918 us; speedup vs baseline: 1.8564x; 1.1887x over previous
//
#include <hip/hip_runtime.h>
#include <math.h>

#define KSZ 5
#define TS 16
#define HALO 3
#define FW (TS + 2*HALO)      // 22
#define FWP (FW + 1)          // 23 (pad)
#define CW (TS + 2)           // 18
#define CWP (CW + 1)          // 19
#define SF_C (FW*FWP)         // 506 floats per flow channel
#define SC_BASE (2*SF_C)      // sc starts here in smf

typedef __attribute__((ext_vector_type(8))) short short8_t;  // 8 bf16
typedef __attribute__((ext_vector_type(4))) float float4_t;
typedef __attribute__((ext_vector_type(2))) unsigned int uint2_t;

static __device__ __forceinline__ unsigned short f2bf(float f) {
    union { float f; unsigned int u; } v; v.f = f;
    return (unsigned short)((v.u + 0x7FFFu + ((v.u >> 16) & 1u)) >> 16);  // RNE
}
// truncating bf16 pack: low16 = hi16(a), high16 = hi16(b) — ONE v_perm_b32
static __device__ __forceinline__ unsigned int pk2t(float a, float b) {
    union { float f; unsigned int u; } ua, ub; ua.f = a; ub.f = b;
    return __builtin_amdgcn_perm(ub.u, ua.u, 0x07060302u);
}

// channel slot n (0..63) of GEMM2 output -> (c, sel, idx); j = sel*15 + idx
// valid iff sel==0 ? idx<15 : idx<10.  tap offset = sel*3*FWP + (idx/5)*FWP + idx%5
static __device__ __forceinline__ void slot_decode(int n, int& c, int& sel, int& idx, bool& valid) {
    int g4c = (n >> 2) & 3;
    c = g4c >> 1; sel = g4c & 1;
    idx = ((n >> 4) << 2) + (n & 3);
    valid = sel ? (idx < 10) : (idx < 15);
}

// ---- one-block pack kernel: weights/biases -> MFMA-fragment order in ws ----
__global__ __launch_bounds__(256)
void pack_kernel(const float* __restrict__ w1, const float* __restrict__ b1,
                 const float* __restrict__ w2, const float* __restrict__ b2,
                 unsigned short* __restrict__ wp, float* __restrict__ bp)
{
    const int tid = threadIdx.x;
    // weight A-frags: f 0..1 = W1 nt, f 2..5 = W2' nt.  entry: wp[(f*64+l)*8 + j]
    // A layout: lane l holds A[m = l&15][k = (l>>4)*8 + j]
    for (int i = tid; i < 6*64*8; i += 256) {
        int f = i >> 9, l = (i >> 3) & 63, j = i & 7;
        int m = l & 15, k = ((l >> 4) << 3) + j;
        float v;
        if (f < 2) { int row = f*16 + m; v = (k < 27) ? w1[row*27 + k] : 0.f; }
        else {
            int n = (f - 2)*16 + m;
            int c, sel, idx; bool valid;
            slot_decode(n, c, sel, idx, valid);
            int jj = sel*15 + idx;
            v = valid ? w2[(c*25 + jj)*32 + k] : 0.f;
        }
        wp[i] = f2bf(v);
    }
    // bias C-frags: entry bp[(f*64+l)*4 + r], C row = (l>>4)*4 + r
    for (int i = tid; i < 6*64*4; i += 256) {
        int f = i >> 8, l = (i >> 2) & 63, r = i & 3, g4 = l >> 4;
        float v;
        if (f < 2) v = b1[f*16 + g4*4 + r];
        else {
            int n = (f - 2)*16 + g4*4 + r;
            int c, sel, idx; bool valid;
            slot_decode(n, c, sel, idx, valid);
            v = valid ? b2[c*25 + sel*15 + idx] : 0.f;
        }
        bp[i] = v;
    }
}

__global__ __launch_bounds__(256)
void refine_kernel(const float* __restrict__ flow,
                   const unsigned short* __restrict__ wp,
                   const float* __restrict__ bp,
                   float* __restrict__ out, int H, int W)
{
    __shared__ float smf[SC_BASE + CW*CWP];       // sf[2][22][23] | sc[18][19]
    __shared__ __align__(16) char dyn[6400];      // rs (phase1) / hb (main)

    const int tid = threadIdx.x;
    const int x0 = blockIdx.x * TS;
    const int y0 = blockIdx.y * TS;
    const int b  = blockIdx.z;

    const int lane = tid & 63;
    const int wave = tid >> 6;
    const int col  = lane & 15;
    const int g4   = lane >> 4;
    const int key  = col >> 2;

    // ---- fragment loads from pre-packed ws ----
    short8_t w1A[2], w2A[4];
    float4_t cb1[2], cb2[4];
    #pragma unroll
    for (int nt = 0; nt < 2; ++nt) {
        w1A[nt] = *(const short8_t*)&wp[(nt*64 + lane)*8];
        cb1[nt] = *(const float4_t*)&bp[(nt*64 + lane)*4];
    }
    #pragma unroll
    for (int nt = 0; nt < 4; ++nt) {
        w2A[nt] = *(const short8_t*)&wp[((2+nt)*64 + lane)*8];
        cb2[nt] = *(const float4_t*)&bp[((2+nt)*64 + lane)*4];
    }

    // ---- phase 0: stage flow tile + halo (zero-padded outside image) ----
    for (int c = 0; c < 2; ++c) {
        const float* src = flow + ((size_t)(b*2+c) * H) * W;
        for (int i = tid; i < FW*FW; i += 256) {
            int ly = i / FW, lx = i - ly*FW;
            int gy = y0 - HALO + ly, gx = x0 - HALO + lx;
            float v = 0.f;
            if (gy >= 0 && gy < H && gx >= 0 && gx < W) v = src[(size_t)gy*W + gx];
            smf[c*SF_C + ly*FWP + lx] = v;
        }
    }
    __syncthreads();

    // ---- phase 1a: horizontal 5-tap sums (s, sum v^2) both channels ----
    {
        float4_t* rs = (float4_t*)dyn;            // [FW][CW]
        for (int i = tid; i < FW*CW; i += 256) {
            int y = i / CW, x = i - y*CW;
            const float* r0 = &smf[y*FWP + x];
            const float* r1 = &smf[SF_C + y*FWP + x];
            float s0 = 0.f, q0 = 0.f, s1 = 0.f, q1 = 0.f;
            #pragma unroll
            for (int dx = 0; dx < KSZ; ++dx) {
                float a = r0[dx]; s0 += a; q0 = fmaf(a, a, q0);
                float c = r1[dx]; s1 += c; q1 = fmaf(c, c, q1);
            }
            rs[i] = (float4_t){s0, q0, s1, q1};
        }
    }
    __syncthreads();

    // ---- phase 1b: vertical 5-row sum -> variance (ddof=1) -> consistency ----
    for (int i = tid; i < CW*CW; i += 256) {
        int py = i / CW, px = i - py*CW;
        int gy = y0 - 1 + py, gx = x0 - 1 + px;
        float cons = 0.f;
        if (gy >= 0 && gy < H && gx >= 0 && gx < W) {
            const float4_t* rp = (const float4_t*)dyn + py*CW + px;
            float4_t acc = rp[0];
            #pragma unroll
            for (int dy = 1; dy < KSZ; ++dy) acc += rp[dy*CW];
            float v0 = (acc.y - acc.x*acc.x*(1.f/25.f)) * (1.f/24.f);
            float v1 = (acc.w - acc.z*acc.z*(1.f/25.f)) * (1.f/24.f);
            cons = __expf(-sqrtf(v0*v0 + v1*v1));
        }
        smf[SC_BASE + py*CWP + px] = cons;
    }
    __syncthreads();   // dyn now reused as hb

    unsigned short* hb = (unsigned short*)dyn;

    // guidance tap bases: k = g4*8 + j; invalid k>=27 -> plane0 (0,0) (W1 col zeroed)
    int goff[8], gpitch[8];
    #pragma unroll
    for (int j = 0; j < 8; ++j) {
        int ch = g4*8 + j;
        int chc = (ch < 27) ? ch : 0;
        int c = chc / 9, rem = chc - 9*c;
        int ky = rem / 3, kx = rem - 3*ky;
        if (c < 2) { goff[j] = c*SF_C + (2+ky)*FWP + (2+kx) + col; gpitch[j] = FWP; }
        else       { goff[j] = SC_BASE + ky*CWP + kx + col;        gpitch[j] = CWP; }
        goff[j] += wave*4 * gpitch[j];
    }

    // patch-tap base: ONE register; taps at compile-time immediates
    const int sel = g4 & 1, pc = g4 >> 1;
    int pb = pc*SF_C + sel*(3*FWP) + FWP + 1 + col + (wave*4)*FWP;

    const int hrow = (wave*16 + col) * 64;       // byte base of this lane's hb row
    const int hw0 = hrow + (((0*2 + (g4 >> 1)) ^ key) << 4) + ((g4 & 1) << 3);
    const int hw1 = hrow + (((1*2 + (g4 >> 1)) ^ key) << 4) + ((g4 & 1) << 3);
    const int hro = hrow + ((g4 ^ key) << 4);

    #pragma unroll
    for (int mt = 0; mt < 4; ++mt) {
        const int ty = wave*4 + mt;

        // guidance B-frag: 8 LDS reads -> 4 perm packs
        unsigned int gd[4];
        #pragma unroll
        for (int t = 0; t < 4; ++t)
            gd[t] = pk2t(smf[goff[2*t]], smf[goff[2*t+1]]);
        #pragma unroll
        for (int j = 0; j < 8; ++j) goff[j] += gpitch[j];
        union { unsigned int u[4]; short8_t s; } gu;
        gu.u[0] = gd[0]; gu.u[1] = gd[1]; gu.u[2] = gd[2]; gu.u[3] = gd[3];
        short8_t gB = gu.s;

        // GEMM1: h = relu(W1 . g + b1)
        float4_t h0 = __builtin_amdgcn_mfma_f32_16x16x32_bf16(w1A[0], gB, cb1[0], 0, 0, 0);
        float4_t h1 = __builtin_amdgcn_mfma_f32_16x16x32_bf16(w1A[1], gB, cb1[1], 0, 0, 0);

        // relu + pack -> swizzled b64 writes
        {
            uint2_t d0, d1;
            d0.x = pk2t(fmaxf(h0[0],0.f), fmaxf(h0[1],0.f));
            d0.y = pk2t(fmaxf(h0[2],0.f), fmaxf(h0[3],0.f));
            d1.x = pk2t(fmaxf(h1[0],0.f), fmaxf(h1[1],0.f));
            d1.y = pk2t(fmaxf(h1[2],0.f), fmaxf(h1[3],0.f));
            *(uint2_t*)((char*)hb + hw0) = d0;
            *(uint2_t*)((char*)hb + hw1) = d1;
        }
        short8_t hf = *(const short8_t*)((char*)hb + hro);

        // GEMM2: ka = W2' . h + b2'  (row n -> (c,sel,idx) per slot_decode)
        float4_t ka[4];
        #pragma unroll
        for (int nt = 0; nt < 4; ++nt)
            ka[nt] = __builtin_amdgcn_mfma_f32_16x16x32_bf16(w2A[nt], hf, cb2[nt], 0, 0, 0);

        // patch dot: 16 taps at immediate offsets from pb (pairs -> ds_read2_b32)
        float s = 0.f;
        #pragma unroll
        for (int idx = 0; idx < 16; ++idx) {
            float pv = smf[pb + (idx/5)*FWP + (idx%5)];
            s = fmaf(ka[idx >> 2][idx & 3], pv, s);
        }
        pb += FWP;

        // combine sel partitions: lanes g4 0<->1 (c=0), 2<->3 (c=1)
        s += __shfl_xor(s, 16);

        if ((g4 & 1) == 0) {
            int y = y0 + ty, x = x0 + col;
            out[((size_t)(b*2 + pc) * H + y) * W + x] = s;
        }
    }
}

extern "C" void kernel_launch(void* const* d_in, const int* in_sizes, int n_in,
                              void* d_out, int out_size, void* d_ws, size_t ws_size,
                              hipStream_t stream) {
    const float* flow = (const float*)d_in[0];
    const float* w1   = (const float*)d_in[1];
    const float* b1   = (const float*)d_in[2];
    const float* w2   = (const float*)d_in[3];
    const float* b2   = (const float*)d_in[4];
    float* out = (float*)d_out;

    unsigned short* wp = (unsigned short*)d_ws;                 // 6*64*8 ushort = 6 KB
    float* bp = (float*)((char*)d_ws + 8192);                   // 6*64*4 float = 6 KB

    const int H = 1024, W = 1024;
    const int B = in_sizes[0] / (2 * H * W);

    pack_kernel<<<1, 256, 0, stream>>>(w1, b1, w2, b2, wp, bp);
    dim3 grid(W / TS, H / TS, B);
    refine_kernel<<<grid, dim3(256), 0, stream>>>(flow, wp, bp, out, H, W);
}

// Round 6
// 126.120 us; speedup vs baseline: 1.9270x; 1.0380x over previous
//
#include <hip/hip_runtime.h>
#include <math.h>

#define KSZ 5
#define TS 16
#define HALO 3
#define FW (TS + 2*HALO)      // 22
#define FWP (FW + 1)          // 23 (pad; ALSO the uniform guidance pitch)
#define CW (TS + 2)           // 18
#define SF_C (FW*FWP)         // 506 floats per flow channel
#define SC_BASE (2*SF_C)      // sc starts here in smf (pitch FWP, 18 rows)
#define SMF_TOT (SC_BASE + 18*FWP)

typedef __attribute__((ext_vector_type(8))) short short8_t;  // 8 bf16
typedef __attribute__((ext_vector_type(4))) float float4_t;
typedef __attribute__((ext_vector_type(2))) unsigned int uint2_t;

static __device__ __forceinline__ unsigned short f2bf(float f) {
    union { float f; unsigned int u; } v; v.f = f;
    return (unsigned short)((v.u + 0x7FFFu + ((v.u >> 16) & 1u)) >> 16);  // RNE
}
// truncating bf16 pack: low16 = hi16(a), high16 = hi16(b) — ONE v_perm_b32
static __device__ __forceinline__ unsigned int pk2t(float a, float b) {
    union { float f; unsigned int u; } ua, ub; ua.f = a; ub.f = b;
    return __builtin_amdgcn_perm(ub.u, ua.u, 0x07060302u);
}

// GEMM2 output slot n -> (c, sel, idx); j = sel*15 + idx; valid: sel?idx<10:idx<15
static __device__ __forceinline__ void slot_decode(int n, int& c, int& sel, int& idx, bool& valid) {
    int g4c = (n >> 2) & 3;
    c = g4c >> 1; sel = g4c & 1;
    idx = ((n >> 4) << 2) + (n & 3);
    valid = sel ? (idx < 10) : (idx < 15);
}

// GEMM1 K-permutation: k-slot s -> original guidance k (c*9 + ky*3 + kx), -1 = zero
static __device__ __forceinline__ int kperm(int s) {
    int sg = s >> 3, sj = s & 7;
    if (sg < 3) return sg*9 + sj;     // plane sg, taps 0..7
    if (sj == 1) return 8;            // c0 tap 8
    if (sj == 2) return 17;           // c1 tap 8
    if (sj == 4) return 26;           // cons tap 8
    return -1;
}

// ---- one-block pack kernel: weights/biases -> MFMA-fragment order in ws ----
__global__ __launch_bounds__(256)
void pack_kernel(const float* __restrict__ w1, const float* __restrict__ b1,
                 const float* __restrict__ w2, const float* __restrict__ b2,
                 unsigned short* __restrict__ wp, float* __restrict__ bp)
{
    const int tid = threadIdx.x;
    // weight A-frags: f 0..1 = W1' nt, f 2..5 = W2' nt.  entry: wp[(f*64+l)*8 + j]
    // A layout: lane l holds A[m = l&15][k-slot = (l>>4)*8 + j]
    for (int i = tid; i < 6*64*8; i += 256) {
        int f = i >> 9, l = (i >> 3) & 63, j = i & 7;
        int m = l & 15, s = ((l >> 4) << 3) + j;
        float v;
        if (f < 2) {
            int k = kperm(s);
            v = (k >= 0) ? w1[(f*16 + m)*27 + k] : 0.f;
        } else {
            int n = (f - 2)*16 + m;
            int c, sel, idx; bool valid;
            slot_decode(n, c, sel, idx, valid);
            v = valid ? w2[(c*25 + sel*15 + idx)*32 + s] : 0.f;
        }
        wp[i] = f2bf(v);
    }
    // bias C-frags: entry bp[(f*64+l)*4 + r], C row = (l>>4)*4 + r
    for (int i = tid; i < 6*64*4; i += 256) {
        int f = i >> 8, l = (i >> 2) & 63, r = i & 3, g4 = l >> 4;
        float v;
        if (f < 2) v = b1[f*16 + g4*4 + r];
        else {
            int n = (f - 2)*16 + g4*4 + r;
            int c, sel, idx; bool valid;
            slot_decode(n, c, sel, idx, valid);
            v = valid ? b2[c*25 + sel*15 + idx] : 0.f;
        }
        bp[i] = v;
    }
}

__global__ __launch_bounds__(256)
void refine_kernel(const float* __restrict__ flow,
                   const unsigned short* __restrict__ wp,
                   const float* __restrict__ bp,
                   float* __restrict__ out, int H, int W)
{
    __shared__ float smf[SMF_TOT];                // sf[2][22][23] | sc[18][23]
    __shared__ __align__(16) char dyn[6400];      // rs[22][18] float4 (ph1) / hb (main)

    const int tid = threadIdx.x;
    const int x0 = blockIdx.x * TS;
    const int y0 = blockIdx.y * TS;
    const int b  = blockIdx.z;

    const int lane = tid & 63;
    const int wave = tid >> 6;
    const int col  = lane & 15;
    const int g4   = lane >> 4;
    const int key  = col >> 2;

    // ---- fragment loads from pre-packed ws ----
    short8_t w1A[2], w2A[4];
    float4_t cb1[2], cb2[4];
    #pragma unroll
    for (int nt = 0; nt < 2; ++nt) {
        w1A[nt] = *(const short8_t*)&wp[(nt*64 + lane)*8];
        cb1[nt] = *(const float4_t*)&bp[(nt*64 + lane)*4];
    }
    #pragma unroll
    for (int nt = 0; nt < 4; ++nt) {
        w2A[nt] = *(const short8_t*)&wp[((2+nt)*64 + lane)*8];
        cb2[nt] = *(const float4_t*)&bp[((2+nt)*64 + lane)*4];
    }

    // ---- phase 0: stage flow tile + halo (zero-padded outside image) ----
    for (int c = 0; c < 2; ++c) {
        const float* src = flow + ((size_t)(b*2+c) * H) * W;
        for (int i = tid; i < FW*FW; i += 256) {
            int ly = i / FW, lx = i - ly*FW;
            int gy = y0 - HALO + ly, gx = x0 - HALO + lx;
            float v = 0.f;
            if (gy >= 0 && gy < H && gx >= 0 && gx < W) v = src[(size_t)gy*W + gx];
            smf[c*SF_C + ly*FWP + lx] = v;
        }
    }
    __syncthreads();

    // ---- phase 1a: horizontal 5-tap sums, 2 adjacent outputs/thread ----
    {
        float4_t* rs = (float4_t*)dyn;            // [FW][CW]
        if (tid < FW*(CW/2)) {                    // 22*9 = 198
            int y = tid / (CW/2), xp = (tid - y*(CW/2)) * 2;
            const float* r0 = &smf[y*FWP + xp];
            const float* r1 = &smf[SF_C + y*FWP + xp];
            float a0=r0[0], a1=r0[1], a2=r0[2], a3=r0[3], a4=r0[4], a5=r0[5];
            float c0=r1[0], c1=r1[1], c2=r1[2], c3=r1[3], c4=r1[4], c5=r1[5];
            float sA = ((a0+a1)+(a2+a3))+a4;
            float qA = fmaf(a4,a4, fmaf(a3,a3, fmaf(a2,a2, fmaf(a1,a1, a0*a0))));
            float sB = ((c0+c1)+(c2+c3))+c4;
            float qB = fmaf(c4,c4, fmaf(c3,c3, fmaf(c2,c2, fmaf(c1,c1, c0*c0))));
            float sA1 = sA + a5 - a0;
            float qA1 = fmaf(-a0, a0, fmaf(a5, a5, qA));
            float sB1 = sB + c5 - c0;
            float qB1 = fmaf(-c0, c0, fmaf(c5, c5, qB));
            rs[y*CW + xp]     = (float4_t){sA,  qA,  sB,  qB };
            rs[y*CW + xp + 1] = (float4_t){sA1, qA1, sB1, qB1};
        }
    }
    __syncthreads();

    // ---- phase 1b: vertical 5-row sum -> variance (ddof=1) -> consistency ----
    for (int i = tid; i < CW*CW; i += 256) {
        int py = i / CW, px = i - py*CW;
        int gy = y0 - 1 + py, gx = x0 - 1 + px;
        float cons = 0.f;
        if (gy >= 0 && gy < H && gx >= 0 && gx < W) {
            const float4_t* rp = (const float4_t*)dyn + py*CW + px;
            float4_t acc = rp[0];
            #pragma unroll
            for (int dy = 1; dy < KSZ; ++dy) acc += rp[dy*CW];
            float v0 = (acc.y - acc.x*acc.x*(1.f/25.f)) * (1.f/24.f);
            float v1 = (acc.w - acc.z*acc.z*(1.f/25.f)) * (1.f/24.f);
            cons = __expf(-sqrtf(v0*v0 + v1*v1));
        }
        smf[SC_BASE + py*FWP + px] = cons;        // sc pitch = FWP (uniform)
    }
    __syncthreads();   // dyn now reused as hb

    unsigned short* hb = (unsigned short*)dyn;

    // guidance bases: g4<3 -> plane g4 window origin; g4==3 -> shifted bases so
    // the uniform immediates {(0,1),(2,23),(24,25),(46,47)} land on the tap-8s.
    int gb0, gb1, gb2, gb3;
    {
        int ty0 = wave*4;
        int p0 = 0*SF_C + (ty0 + 2)*FWP + (col + 2);
        int p1 = 1*SF_C + (ty0 + 2)*FWP + (col + 2);
        int p2 = SC_BASE + ty0*FWP + col;
        if (g4 == 0)      { gb0 = gb1 = gb2 = gb3 = p0; }
        else if (g4 == 1) { gb0 = gb1 = gb2 = gb3 = p1; }
        else if (g4 == 2) { gb0 = gb1 = gb2 = gb3 = p2; }
        else { gb0 = p0 + 47; gb1 = p1 + 46; gb2 = p2 + 24; gb3 = p0; }
    }

    // patch-tap base + register pipeline (15 taps; idx15 dropped — ka there is 0)
    const int sel = g4 & 1, pc = g4 >> 1;
    int pb = pc*SF_C + sel*(3*FWP) + FWP + 1 + col + (wave*4)*FWP;
    float pv[15];
    #pragma unroll
    for (int i = 0; i < 15; ++i) pv[i] = smf[pb + (i/5)*FWP + (i%5)];

    const int hrow = (wave*16 + col) * 64;       // byte base of this lane's hb row
    const int hw0 = hrow + (((0*2 + (g4 >> 1)) ^ key) << 4) + ((g4 & 1) << 3);
    const int hw1 = hrow + (((1*2 + (g4 >> 1)) ^ key) << 4) + ((g4 & 1) << 3);
    const int hro = hrow + ((g4 ^ key) << 4);

    #pragma unroll
    for (int mt = 0; mt < 4; ++mt) {
        const int ty = wave*4 + mt;

        // guidance B-frag: 4 ds_read2_b32 (uniform immediates) + 4 perm packs
        float ga = smf[gb0 + 0],  gbv = smf[gb0 + 1];
        float gc = smf[gb1 + 2],  gd  = smf[gb1 + 23];
        float ge = smf[gb2 + 24], gf  = smf[gb2 + 25];
        float gg = smf[gb3 + 46], gh  = smf[gb3 + 47];
        union { unsigned int u[4]; short8_t s; } gu;
        gu.u[0] = pk2t(ga, gbv); gu.u[1] = pk2t(gc, gd);
        gu.u[2] = pk2t(ge, gf);  gu.u[3] = pk2t(gg, gh);
        short8_t gB = gu.s;
        gb0 += FWP; gb1 += FWP; gb2 += FWP; gb3 += FWP;

        // GEMM1: h = relu(W1' . g + b1)
        float4_t h0 = __builtin_amdgcn_mfma_f32_16x16x32_bf16(w1A[0], gB, cb1[0], 0, 0, 0);
        float4_t h1 = __builtin_amdgcn_mfma_f32_16x16x32_bf16(w1A[1], gB, cb1[1], 0, 0, 0);

        // relu + pack -> swizzled b64 writes
        {
            uint2_t d0, d1;
            d0.x = pk2t(fmaxf(h0[0],0.f), fmaxf(h0[1],0.f));
            d0.y = pk2t(fmaxf(h0[2],0.f), fmaxf(h0[3],0.f));
            d1.x = pk2t(fmaxf(h1[0],0.f), fmaxf(h1[1],0.f));
            d1.y = pk2t(fmaxf(h1[2],0.f), fmaxf(h1[3],0.f));
            *(uint2_t*)((char*)hb + hw0) = d0;
            *(uint2_t*)((char*)hb + hw1) = d1;
        }
        short8_t hf = *(const short8_t*)((char*)hb + hro);

        // GEMM2: ka = W2' . h + b2'
        float4_t ka[4];
        #pragma unroll
        for (int nt = 0; nt < 4; ++nt)
            ka[nt] = __builtin_amdgcn_mfma_f32_16x16x32_bf16(w2A[nt], hf, cb2[nt], 0, 0, 0);

        // patch dot from the register pipeline (15 taps; idx15 has ka==0)
        float s = 0.f;
        #pragma unroll
        for (int i = 0; i < 15; ++i)
            s = fmaf(ka[i >> 2][i & 3], pv[i], s);

        if (mt < 3) {   // advance pipeline: rows shift by one (tap(i,mt+1)=tap(i+5,mt))
            #pragma unroll
            for (int i = 0; i < 10; ++i) pv[i] = pv[i + 5];
            pb += FWP;
            #pragma unroll
            for (int i = 10; i < 15; ++i) pv[i] = smf[pb + (i/5)*FWP + (i%5)];
        }

        // combine sel partitions: lanes g4 0<->1 (c=0), 2<->3 (c=1)
        s += __shfl_xor(s, 16);

        if ((g4 & 1) == 0) {
            int y = y0 + ty, x = x0 + col;
            out[((size_t)(b*2 + pc) * H + y) * W + x] = s;
        }
    }
}

extern "C" void kernel_launch(void* const* d_in, const int* in_sizes, int n_in,
                              void* d_out, int out_size, void* d_ws, size_t ws_size,
                              hipStream_t stream) {
    const float* flow = (const float*)d_in[0];
    const float* w1   = (const float*)d_in[1];
    const float* b1   = (const float*)d_in[2];
    const float* w2   = (const float*)d_in[3];
    const float* b2   = (const float*)d_in[4];
    float* out = (float*)d_out;

    unsigned short* wp = (unsigned short*)d_ws;                 // 6*64*8 ushort = 6 KB
    float* bp = (float*)((char*)d_ws + 8192);                   // 6*64*4 float = 6 KB

    const int H = 1024, W = 1024;
    const int B = in_sizes[0] / (2 * H * W);

    pack_kernel<<<1, 256, 0, stream>>>(w1, b1, w2, b2, wp, bp);
    dim3 grid(W / TS, H / TS, B);
    refine_kernel<<<grid, dim3(256), 0, stream>>>(flow, wp, bp, out, H, W);
}

// Round 7
// 118.716 us; speedup vs baseline: 2.0472x; 1.0624x over previous
//
#include <hip/hip_runtime.h>
#include <math.h>

#define KSZ 5
#define TSX 16                // tile width (MFMA N = 16 pixels)
#define TSY 32                // tile height (each wave: 8 rows)
#define HALO 3
#define FWX 22                // staged cols = TSX + 6
#define FH  38                // staged rows = TSY + 6
#define PITCH 23              // uniform pitch for sf planes AND sc plane
#define SF_C (FH*PITCH)       // 874 floats per flow channel
#define SC_BASE (2*SF_C)      // sc: 34 rows x pitch 23
#define SMF_TOT (SC_BASE + 34*PITCH)

typedef __attribute__((ext_vector_type(8))) short short8_t;  // 8 bf16
typedef __attribute__((ext_vector_type(4))) float float4_t;
typedef __attribute__((ext_vector_type(2))) unsigned int uint2_t;

static __device__ __forceinline__ unsigned short f2bf(float f) {
    union { float f; unsigned int u; } v; v.f = f;
    return (unsigned short)((v.u + 0x7FFFu + ((v.u >> 16) & 1u)) >> 16);  // RNE
}
// truncating bf16 pack: low16 = hi16(a), high16 = hi16(b) — ONE v_perm_b32
static __device__ __forceinline__ unsigned int pk2t(float a, float b) {
    union { float f; unsigned int u; } ua, ub; ua.f = a; ub.f = b;
    return __builtin_amdgcn_perm(ub.u, ua.u, 0x07060302u);
}

// GEMM2 output slot n -> (c, sel, idx); j = sel*15 + idx; valid: sel?idx<10:idx<15
static __device__ __forceinline__ void slot_decode(int n, int& c, int& sel, int& idx, bool& valid) {
    int g4c = (n >> 2) & 3;
    c = g4c >> 1; sel = g4c & 1;
    idx = ((n >> 4) << 2) + (n & 3);
    valid = sel ? (idx < 10) : (idx < 15);
}

// GEMM1 K-permutation: k-slot s -> original guidance k (c*9 + ky*3 + kx), -1 = zero
static __device__ __forceinline__ int kperm(int s) {
    int sg = s >> 3, sj = s & 7;
    if (sg < 3) return sg*9 + sj;     // plane sg, taps 0..7
    if (sj == 1) return 8;            // c0 tap 8
    if (sj == 2) return 17;           // c1 tap 8
    if (sj == 4) return 26;           // cons tap 8
    return -1;
}

// ---- one-block pack kernel: weights/biases -> MFMA-fragment order in ws ----
__global__ __launch_bounds__(256)
void pack_kernel(const float* __restrict__ w1, const float* __restrict__ b1,
                 const float* __restrict__ w2, const float* __restrict__ b2,
                 unsigned short* __restrict__ wp, float* __restrict__ bp)
{
    const int tid = threadIdx.x;
    for (int i = tid; i < 6*64*8; i += 256) {
        int f = i >> 9, l = (i >> 3) & 63, j = i & 7;
        int m = l & 15, s = ((l >> 4) << 3) + j;
        float v;
        if (f < 2) {
            int k = kperm(s);
            v = (k >= 0) ? w1[(f*16 + m)*27 + k] : 0.f;
        } else {
            int n = (f - 2)*16 + m;
            int c, sel, idx; bool valid;
            slot_decode(n, c, sel, idx, valid);
            v = valid ? w2[(c*25 + sel*15 + idx)*32 + s] : 0.f;
        }
        wp[i] = f2bf(v);
    }
    for (int i = tid; i < 6*64*4; i += 256) {
        int f = i >> 8, l = (i >> 2) & 63, r = i & 3, g4 = l >> 4;
        float v;
        if (f < 2) v = b1[f*16 + g4*4 + r];
        else {
            int n = (f - 2)*16 + g4*4 + r;
            int c, sel, idx; bool valid;
            slot_decode(n, c, sel, idx, valid);
            v = valid ? b2[c*25 + sel*15 + idx] : 0.f;
        }
        bp[i] = v;
    }
}

__global__ __launch_bounds__(256)
void refine_kernel(const float* __restrict__ flow,
                   const unsigned short* __restrict__ wp,
                   const float* __restrict__ bp,
                   float* __restrict__ out, int H, int W)
{
    __shared__ float smf[SMF_TOT];                 // sf[2][38][23] | sc[34][23]
    __shared__ __align__(16) char dyn[10960];      // rs[38][18] float4 (ph1) / hb (main)

    const int tid = threadIdx.x;
    const int x0 = blockIdx.x * TSX;
    const int y0 = blockIdx.y * TSY;
    const int b  = blockIdx.z;

    const int lane = tid & 63;
    const int wave = tid >> 6;
    const int col  = lane & 15;
    const int g4   = lane >> 4;
    const int key  = col >> 2;

    // ---- fragment loads from pre-packed ws ----
    short8_t w1A[2], w2A[4];
    float4_t cb1[2], cb2[4];
    #pragma unroll
    for (int nt = 0; nt < 2; ++nt) {
        w1A[nt] = *(const short8_t*)&wp[(nt*64 + lane)*8];
        cb1[nt] = *(const float4_t*)&bp[(nt*64 + lane)*4];
    }
    #pragma unroll
    for (int nt = 0; nt < 4; ++nt) {
        w2A[nt] = *(const short8_t*)&wp[((2+nt)*64 + lane)*8];
        cb2[nt] = *(const float4_t*)&bp[((2+nt)*64 + lane)*4];
    }

    // ---- phase 0: stage flow tile + halo; interior fast path (91% of blocks) ----
    {
        const float* srcb = flow + (size_t)(b*2) * H * W;
        if (x0 >= HALO && x0 + TSX + HALO <= W && y0 >= HALO && y0 + TSY + HALO <= H) {
            const float* s = srcb + (size_t)(y0 - HALO) * W + (x0 - HALO);
            for (int i = tid; i < 2*FH*FWX; i += 256) {
                int c = 0, r = i;
                if (r >= FH*FWX) { c = 1; r -= FH*FWX; }
                int ly = r / FWX, lx = r - ly*FWX;
                smf[c*SF_C + ly*PITCH + lx] = s[(size_t)c*H*W + ly*W + lx];
            }
        } else {
            for (int i = tid; i < 2*FH*FWX; i += 256) {
                int c = 0, r = i;
                if (r >= FH*FWX) { c = 1; r -= FH*FWX; }
                int ly = r / FWX, lx = r - ly*FWX;
                int gy = y0 - HALO + ly, gx = x0 - HALO + lx;
                float v = 0.f;
                if (gy >= 0 && gy < H && gx >= 0 && gx < W)
                    v = srcb[(size_t)c*H*W + (size_t)gy*W + gx];
                smf[c*SF_C + ly*PITCH + lx] = v;
            }
        }
    }
    __syncthreads();

    // ---- phase 1a: horizontal 5-tap sums (s, sum v^2), 2 adjacent outputs ----
    {
        float4_t* rs = (float4_t*)dyn;            // [FH][18]
        for (int i = tid; i < FH*9; i += 256) {   // 342 units
            int y = i / 9, xp = (i - y*9) * 2;
            const float* r0 = &smf[y*PITCH + xp];
            const float* r1 = &smf[SF_C + y*PITCH + xp];
            float a0=r0[0], a1=r0[1], a2=r0[2], a3=r0[3], a4=r0[4], a5=r0[5];
            float c0=r1[0], c1=r1[1], c2=r1[2], c3=r1[3], c4=r1[4], c5=r1[5];
            float sA = ((a0+a1)+(a2+a3))+a4;
            float qA = fmaf(a4,a4, fmaf(a3,a3, fmaf(a2,a2, fmaf(a1,a1, a0*a0))));
            float sB = ((c0+c1)+(c2+c3))+c4;
            float qB = fmaf(c4,c4, fmaf(c3,c3, fmaf(c2,c2, fmaf(c1,c1, c0*c0))));
            float sA1 = sA + a5 - a0;
            float qA1 = fmaf(-a0, a0, fmaf(a5, a5, qA));
            float sB1 = sB + c5 - c0;
            float qB1 = fmaf(-c0, c0, fmaf(c5, c5, qB));
            rs[y*18 + xp]     = (float4_t){sA,  qA,  sB,  qB };
            rs[y*18 + xp + 1] = (float4_t){sA1, qA1, sB1, qB1};
        }
    }
    __syncthreads();

    // ---- phase 1b: vertical 5-row sum -> variance (ddof=1) -> consistency ----
    for (int i = tid; i < 34*18; i += 256) {      // 612 units
        int py = i / 18, px = i - py*18;
        int gy = y0 - 1 + py, gx = x0 - 1 + px;
        float cons = 0.f;                          // guidance outside image is 0
        if (gy >= 0 && gy < H && gx >= 0 && gx < W) {
            const float4_t* rp = (const float4_t*)dyn + py*18 + px;
            float4_t acc = rp[0];
            #pragma unroll
            for (int dy = 1; dy < KSZ; ++dy) acc += rp[dy*18];
            float v0 = (acc.y - acc.x*acc.x*(1.f/25.f)) * (1.f/24.f);
            float v1 = (acc.w - acc.z*acc.z*(1.f/25.f)) * (1.f/24.f);
            cons = __expf(-sqrtf(v0*v0 + v1*v1));
        }
        smf[SC_BASE + py*PITCH + px] = cons;
    }
    __syncthreads();   // dyn now reused as hb

    unsigned short* hb = (unsigned short*)dyn;

    // guidance bases (pitch 23 everywhere): g4<3 -> plane g4 window origin;
    // g4==3 -> shifted bases so uniform immediates {(0,1),(2,23),(24,25),(46,47)}
    // land on the three tap-8s (slots 1,2,4); other slots ride zeroed W1 columns.
    int gb0, gb1, gb2, gb3;
    {
        int ty0 = wave*8;
        int p0 = 0*SF_C + (ty0 + 2)*PITCH + (col + 2);
        int p1 = 1*SF_C + (ty0 + 2)*PITCH + (col + 2);
        int p2 = SC_BASE + ty0*PITCH + col;
        if (g4 == 0)      { gb0 = gb1 = gb2 = gb3 = p0; }
        else if (g4 == 1) { gb0 = gb1 = gb2 = gb3 = p1; }
        else if (g4 == 2) { gb0 = gb1 = gb2 = gb3 = p2; }
        else { gb0 = p0 + 47; gb1 = p1 + 46; gb2 = p2 + 24; gb3 = p0; }
    }

    // patch-tap base + register pipeline (15 taps; idx15 dropped — its ka is 0)
    const int sel = g4 & 1, pc = g4 >> 1;
    int pb = pc*SF_C + sel*(3*PITCH) + PITCH + 1 + col + (wave*8)*PITCH;
    float pv[15];
    #pragma unroll
    for (int i = 0; i < 15; ++i) pv[i] = smf[pb + (i/5)*PITCH + (i%5)];

    const int hrow = (wave*16 + col) * 64;       // byte base of this lane's hb row
    const int hw0 = hrow + (((0*2 + pc) ^ key) << 4) + (sel << 3);
    const int hw1 = hrow + (((1*2 + pc) ^ key) << 4) + (sel << 3);
    const int hro = hrow + ((g4 ^ key) << 4);

    #pragma unroll
    for (int mt = 0; mt < 8; ++mt) {
        const int ty = wave*8 + mt;

        // guidance B-frag: 4 ds_read2_b32 (uniform immediates) + 4 perm packs
        float ga = smf[gb0 + 0],  gbv = smf[gb0 + 1];
        float gc = smf[gb1 + 2],  gd  = smf[gb1 + 23];
        float ge = smf[gb2 + 24], gf  = smf[gb2 + 25];
        float gg = smf[gb3 + 46], gh  = smf[gb3 + 47];
        union { unsigned int u[4]; short8_t s; } gu;
        gu.u[0] = pk2t(ga, gbv); gu.u[1] = pk2t(gc, gd);
        gu.u[2] = pk2t(ge, gf);  gu.u[3] = pk2t(gg, gh);
        short8_t gB = gu.s;
        gb0 += PITCH; gb1 += PITCH; gb2 += PITCH; gb3 += PITCH;

        // GEMM1: h = relu(W1' . g + b1)
        float4_t h0 = __builtin_amdgcn_mfma_f32_16x16x32_bf16(w1A[0], gB, cb1[0], 0, 0, 0);
        float4_t h1 = __builtin_amdgcn_mfma_f32_16x16x32_bf16(w1A[1], gB, cb1[1], 0, 0, 0);

        // relu + pack -> swizzled b64 writes
        {
            uint2_t d0, d1;
            d0.x = pk2t(fmaxf(h0[0],0.f), fmaxf(h0[1],0.f));
            d0.y = pk2t(fmaxf(h0[2],0.f), fmaxf(h0[3],0.f));
            d1.x = pk2t(fmaxf(h1[0],0.f), fmaxf(h1[1],0.f));
            d1.y = pk2t(fmaxf(h1[2],0.f), fmaxf(h1[3],0.f));
            *(uint2_t*)((char*)hb + hw0) = d0;
            *(uint2_t*)((char*)hb + hw1) = d1;
        }
        short8_t hf = *(const short8_t*)((char*)hb + hro);

        // GEMM2: ka = W2' . h + b2'
        float4_t ka[4];
        #pragma unroll
        for (int nt = 0; nt < 4; ++nt)
            ka[nt] = __builtin_amdgcn_mfma_f32_16x16x32_bf16(w2A[nt], hf, cb2[nt], 0, 0, 0);

        // patch dot from the register pipeline
        float s = 0.f;
        #pragma unroll
        for (int i = 0; i < 15; ++i)
            s = fmaf(ka[i >> 2][i & 3], pv[i], s);

        if (mt < 7) {   // advance pipeline: tap(i,mt+1) = tap(i+5,mt)
            #pragma unroll
            for (int i = 0; i < 10; ++i) pv[i] = pv[i + 5];
            pb += PITCH;
            #pragma unroll
            for (int i = 10; i < 15; ++i) pv[i] = smf[pb + (i/5)*PITCH + (i%5)];
        }

        // combine sel partitions: lanes g4 0<->1 (c=0), 2<->3 (c=1)
        s += __shfl_xor(s, 16);

        if (sel == 0) {
            int y = y0 + ty, x = x0 + col;
            out[((size_t)(b*2 + pc) * H + y) * W + x] = s;
        }
    }
}

extern "C" void kernel_launch(void* const* d_in, const int* in_sizes, int n_in,
                              void* d_out, int out_size, void* d_ws, size_t ws_size,
                              hipStream_t stream) {
    const float* flow = (const float*)d_in[0];
    const float* w1   = (const float*)d_in[1];
    const float* b1   = (const float*)d_in[2];
    const float* w2   = (const float*)d_in[3];
    const float* b2   = (const float*)d_in[4];
    float* out = (float*)d_out;

    unsigned short* wp = (unsigned short*)d_ws;                 // 6*64*8 ushort = 6 KB
    float* bp = (float*)((char*)d_ws + 8192);                   // 6*64*4 float = 6 KB

    const int H = 1024, W = 1024;
    const int B = in_sizes[0] / (2 * H * W);

    pack_kernel<<<1, 256, 0, stream>>>(w1, b1, w2, b2, wp, bp);
    dim3 grid(W / TSX, H / TSY, B);
    refine_kernel<<<grid, dim3(256), 0, stream>>>(flow, wp, bp, out, H, W);
}

// Round 8
// 115.568 us; speedup vs baseline: 2.1029x; 1.0272x over previous
//
#include <hip/hip_runtime.h>
#include <math.h>

#define KSZ 5
#define TSX 16                // tile width (MFMA N = 16 pixels)
#define TSY 64                // tile height (each wave: 16 rows)
#define HALO 3
#define FWX 22                // staged cols = TSX + 6
#define FH  70                // staged rows = TSY + 6
#define SCH 66                // sc rows = TSY + 2
#define PITCH 23              // uniform pitch for sf planes AND sc plane
#define SF_C (FH*PITCH)       // 1610 floats per flow channel
#define SC_BASE (2*SF_C)
#define SMF_TOT (SC_BASE + SCH*PITCH)

typedef __attribute__((ext_vector_type(8))) short short8_t;  // 8 bf16
typedef __attribute__((ext_vector_type(4))) float float4_t;

static __device__ __forceinline__ unsigned short f2bf(float f) {
    union { float f; unsigned int u; } v; v.f = f;
    return (unsigned short)((v.u + 0x7FFFu + ((v.u >> 16) & 1u)) >> 16);  // RNE
}
// truncating bf16 pack: low16 = hi16(a), high16 = hi16(b) — ONE v_perm_b32
static __device__ __forceinline__ unsigned int pk2t(float a, float b) {
    union { float f; unsigned int u; } ua, ub; ua.f = a; ub.f = b;
    return __builtin_amdgcn_perm(ub.u, ua.u, 0x07060302u);
}

// GEMM2 output slot n -> (c, sel, idx); j = sel*15 + idx; valid: sel?idx<10:idx<15
static __device__ __forceinline__ void slot_decode(int n, int& c, int& sel, int& idx, bool& valid) {
    int g4c = (n >> 2) & 3;
    c = g4c >> 1; sel = g4c & 1;
    idx = ((n >> 4) << 2) + (n & 3);
    valid = sel ? (idx < 10) : (idx < 15);
}

// GEMM1 K-permutation: k-slot s -> original guidance k (c*9 + ky*3 + kx), -1 = zero
static __device__ __forceinline__ int kperm(int s) {
    int sg = s >> 3, sj = s & 7;
    if (sg < 3) return sg*9 + sj;     // plane sg, taps 0..7
    if (sj == 1) return 8;            // c0 tap 8
    if (sj == 2) return 17;           // c1 tap 8
    if (sj == 4) return 26;           // cons tap 8
    return -1;
}

// GEMM2 K-permutation: k-slot s -> h channel the owning lane already holds.
// Lane g4 holds C rows {g4*4+r} (h0) and {16+g4*4+r} (h1): j<4 -> h0[j], j>=4 -> h1[j-4]
static __device__ __forceinline__ int kperm2(int s) {
    int g = s >> 3, j = s & 7;
    return (j < 4) ? (g*4 + j) : (16 + g*4 + (j - 4));
}

// ---- one-block pack kernel: weights/biases -> MFMA-fragment order in ws ----
__global__ __launch_bounds__(256)
void pack_kernel(const float* __restrict__ w1, const float* __restrict__ b1,
                 const float* __restrict__ w2, const float* __restrict__ b2,
                 unsigned short* __restrict__ wp, float* __restrict__ bp)
{
    const int tid = threadIdx.x;
    for (int i = tid; i < 6*64*8; i += 256) {
        int f = i >> 9, l = (i >> 3) & 63, j = i & 7;
        int m = l & 15, s = ((l >> 4) << 3) + j;
        float v;
        if (f < 2) {
            int k = kperm(s);
            v = (k >= 0) ? w1[(f*16 + m)*27 + k] : 0.f;
        } else {
            int n = (f - 2)*16 + m;
            int c, sel, idx; bool valid;
            slot_decode(n, c, sel, idx, valid);
            v = valid ? w2[(c*25 + sel*15 + idx)*32 + kperm2(s)] : 0.f;
        }
        wp[i] = f2bf(v);
    }
    for (int i = tid; i < 6*64*4; i += 256) {
        int f = i >> 8, l = (i >> 2) & 63, r = i & 3, g4 = l >> 4;
        float v;
        if (f < 2) v = b1[f*16 + g4*4 + r];
        else {
            int n = (f - 2)*16 + g4*4 + r;
            int c, sel, idx; bool valid;
            slot_decode(n, c, sel, idx, valid);
            v = valid ? b2[c*25 + sel*15 + idx] : 0.f;
        }
        bp[i] = v;
    }
}

__global__ __launch_bounds__(256)
void refine_kernel(const float* __restrict__ flow,
                   const unsigned short* __restrict__ wp,
                   const float* __restrict__ bp,
                   float* __restrict__ out, int H, int W)
{
    __shared__ float smf[SMF_TOT];                 // sf[2][70][23] | sc[66][23]
    __shared__ __align__(16) float4_t rs[FH*18];   // horizontal 5-tap sums

    const int tid = threadIdx.x;
    const int x0 = blockIdx.x * TSX;
    const int y0 = blockIdx.y * TSY;
    const int b  = blockIdx.z;

    const int lane = tid & 63;
    const int wave = tid >> 6;
    const int col  = lane & 15;
    const int g4   = lane >> 4;

    // ---- fragment loads from pre-packed ws ----
    short8_t w1A[2], w2A[4];
    float4_t cb1[2], cb2[4];
    #pragma unroll
    for (int nt = 0; nt < 2; ++nt) {
        w1A[nt] = *(const short8_t*)&wp[(nt*64 + lane)*8];
        cb1[nt] = *(const float4_t*)&bp[(nt*64 + lane)*4];
    }
    #pragma unroll
    for (int nt = 0; nt < 4; ++nt) {
        w2A[nt] = *(const short8_t*)&wp[((2+nt)*64 + lane)*8];
        cb2[nt] = *(const float4_t*)&bp[((2+nt)*64 + lane)*4];
    }

    // ---- phase 0: stage flow tile + halo; interior fast path ----
    {
        const float* srcb = flow + (size_t)(b*2) * H * W;
        if (x0 >= HALO && x0 + TSX + HALO <= W && y0 >= HALO && y0 + TSY + HALO <= H) {
            const float* s = srcb + (size_t)(y0 - HALO) * W + (x0 - HALO);
            for (int i = tid; i < 2*FH*FWX; i += 256) {
                int c = 0, r = i;
                if (r >= FH*FWX) { c = 1; r -= FH*FWX; }
                int ly = r / FWX, lx = r - ly*FWX;
                smf[c*SF_C + ly*PITCH + lx] = s[(size_t)c*H*W + ly*W + lx];
            }
        } else {
            for (int i = tid; i < 2*FH*FWX; i += 256) {
                int c = 0, r = i;
                if (r >= FH*FWX) { c = 1; r -= FH*FWX; }
                int ly = r / FWX, lx = r - ly*FWX;
                int gy = y0 - HALO + ly, gx = x0 - HALO + lx;
                float v = 0.f;
                if (gy >= 0 && gy < H && gx >= 0 && gx < W)
                    v = srcb[(size_t)c*H*W + (size_t)gy*W + gx];
                smf[c*SF_C + ly*PITCH + lx] = v;
            }
        }
    }
    __syncthreads();

    // ---- phase 1a: horizontal 5-tap sums (s, sum v^2), 2 adjacent outputs ----
    for (int i = tid; i < FH*9; i += 256) {        // 630 units
        int y = i / 9, xp = (i - y*9) * 2;
        const float* r0 = &smf[y*PITCH + xp];
        const float* r1 = &smf[SF_C + y*PITCH + xp];
        float a0=r0[0], a1=r0[1], a2=r0[2], a3=r0[3], a4=r0[4], a5=r0[5];
        float c0=r1[0], c1=r1[1], c2=r1[2], c3=r1[3], c4=r1[4], c5=r1[5];
        float sA = ((a0+a1)+(a2+a3))+a4;
        float qA = fmaf(a4,a4, fmaf(a3,a3, fmaf(a2,a2, fmaf(a1,a1, a0*a0))));
        float sB = ((c0+c1)+(c2+c3))+c4;
        float qB = fmaf(c4,c4, fmaf(c3,c3, fmaf(c2,c2, fmaf(c1,c1, c0*c0))));
        float sA1 = sA + a5 - a0;
        float qA1 = fmaf(-a0, a0, fmaf(a5, a5, qA));
        float sB1 = sB + c5 - c0;
        float qB1 = fmaf(-c0, c0, fmaf(c5, c5, qB));
        rs[y*18 + xp]     = (float4_t){sA,  qA,  sB,  qB };
        rs[y*18 + xp + 1] = (float4_t){sA1, qA1, sB1, qB1};
    }
    __syncthreads();

    // ---- phase 1b: vertical 5-row sum -> variance (ddof=1) -> consistency ----
    for (int i = tid; i < SCH*18; i += 256) {      // 1188 units
        int py = i / 18, px = i - py*18;
        int gy = y0 - 1 + py, gx = x0 - 1 + px;
        float cons = 0.f;                          // guidance outside image is 0
        if (gy >= 0 && gy < H && gx >= 0 && gx < W) {
            const float4_t* rp = rs + py*18 + px;
            float4_t acc = rp[0];
            #pragma unroll
            for (int dy = 1; dy < KSZ; ++dy) acc += rp[dy*18];
            float v0 = (acc.y - acc.x*acc.x*(1.f/25.f)) * (1.f/24.f);
            float v1 = (acc.w - acc.z*acc.z*(1.f/25.f)) * (1.f/24.f);
            cons = __expf(-sqrtf(v0*v0 + v1*v1));
        }
        smf[SC_BASE + py*PITCH + px] = cons;
    }
    __syncthreads();

    // guidance bases (pitch 23 everywhere): g4<3 -> plane g4 window origin;
    // g4==3 -> shifted bases so uniform immediates {(0,1),(2,23),(24,25),(46,47)}
    // land on the three tap-8s (slots 1,2,4); other slots ride zeroed W1 columns.
    int gb0, gb1, gb2, gb3;
    {
        int ty0 = wave*16;
        int p0 = 0*SF_C + (ty0 + 2)*PITCH + (col + 2);
        int p1 = 1*SF_C + (ty0 + 2)*PITCH + (col + 2);
        int p2 = SC_BASE + ty0*PITCH + col;
        if (g4 == 0)      { gb0 = gb1 = gb2 = gb3 = p0; }
        else if (g4 == 1) { gb0 = gb1 = gb2 = gb3 = p1; }
        else if (g4 == 2) { gb0 = gb1 = gb2 = gb3 = p2; }
        else { gb0 = p0 + 47; gb1 = p1 + 46; gb2 = p2 + 24; gb3 = p0; }
    }

    // patch-tap base + register pipeline (15 taps; idx15 dropped — its ka is 0)
    const int sel = g4 & 1, pc = g4 >> 1;
    int pb = pc*SF_C + sel*(3*PITCH) + PITCH + 1 + col + (wave*16)*PITCH;
    float pv[15];
    #pragma unroll
    for (int i = 0; i < 15; ++i) pv[i] = smf[pb + (i/5)*PITCH + (i%5)];

    #pragma unroll
    for (int mt = 0; mt < 16; ++mt) {
        const int ty = wave*16 + mt;

        // guidance B-frag: 4 ds_read2_b32 (uniform immediates) + 4 perm packs
        float ga = smf[gb0 + 0],  gbv = smf[gb0 + 1];
        float gc = smf[gb1 + 2],  gd  = smf[gb1 + 23];
        float ge = smf[gb2 + 24], gf  = smf[gb2 + 25];
        float gg = smf[gb3 + 46], gh  = smf[gb3 + 47];
        union { unsigned int u[4]; short8_t s; } gu;
        gu.u[0] = pk2t(ga, gbv); gu.u[1] = pk2t(gc, gd);
        gu.u[2] = pk2t(ge, gf);  gu.u[3] = pk2t(gg, gh);
        short8_t gB = gu.s;
        gb0 += PITCH; gb1 += PITCH; gb2 += PITCH; gb3 += PITCH;

        // GEMM1: h = relu(W1' . g + b1)
        float4_t h0 = __builtin_amdgcn_mfma_f32_16x16x32_bf16(w1A[0], gB, cb1[0], 0, 0, 0);
        float4_t h1 = __builtin_amdgcn_mfma_f32_16x16x32_bf16(w1A[1], gB, cb1[1], 0, 0, 0);

        // h B-frag built IN REGISTERS (kperm2 matches W2' K-order) — no LDS roundtrip
        union { unsigned int u[4]; short8_t s; } hu;
        hu.u[0] = pk2t(fmaxf(h0[0],0.f), fmaxf(h0[1],0.f));
        hu.u[1] = pk2t(fmaxf(h0[2],0.f), fmaxf(h0[3],0.f));
        hu.u[2] = pk2t(fmaxf(h1[0],0.f), fmaxf(h1[1],0.f));
        hu.u[3] = pk2t(fmaxf(h1[2],0.f), fmaxf(h1[3],0.f));
        short8_t hf = hu.s;

        // GEMM2: ka = W2' . h + b2'
        float4_t ka[4];
        #pragma unroll
        for (int nt = 0; nt < 4; ++nt)
            ka[nt] = __builtin_amdgcn_mfma_f32_16x16x32_bf16(w2A[nt], hf, cb2[nt], 0, 0, 0);

        // patch dot from the register pipeline
        float s = 0.f;
        #pragma unroll
        for (int i = 0; i < 15; ++i)
            s = fmaf(ka[i >> 2][i & 3], pv[i], s);

        if (mt < 15) {  // advance pipeline: tap(i,mt+1) = tap(i+5,mt)
            #pragma unroll
            for (int i = 0; i < 10; ++i) pv[i] = pv[i + 5];
            pb += PITCH;
            #pragma unroll
            for (int i = 10; i < 15; ++i) pv[i] = smf[pb + (i/5)*PITCH + (i%5)];
        }

        // combine sel partitions: lanes g4 0<->1 (c=0), 2<->3 (c=1)
        s += __shfl_xor(s, 16);

        if (sel == 0) {
            int y = y0 + ty, x = x0 + col;
            out[((size_t)(b*2 + pc) * H + y) * W + x] = s;
        }
    }
}

extern "C" void kernel_launch(void* const* d_in, const int* in_sizes, int n_in,
                              void* d_out, int out_size, void* d_ws, size_t ws_size,
                              hipStream_t stream) {
    const float* flow = (const float*)d_in[0];
    const float* w1   = (const float*)d_in[1];
    const float* b1   = (const float*)d_in[2];
    const float* w2   = (const float*)d_in[3];
    const float* b2   = (const float*)d_in[4];
    float* out = (float*)d_out;

    unsigned short* wp = (unsigned short*)d_ws;                 // 6*64*8 ushort = 6 KB
    float* bp = (float*)((char*)d_ws + 8192);                   // 6*64*4 float = 6 KB

    const int H = 1024, W = 1024;
    const int B = in_sizes[0] / (2 * H * W);

    pack_kernel<<<1, 256, 0, stream>>>(w1, b1, w2, b2, wp, bp);
    dim3 grid(W / TSX, H / TSY, B);
    refine_kernel<<<grid, dim3(256), 0, stream>>>(flow, wp, bp, out, H, W);
}

// Round 9
// 112.579 us; speedup vs baseline: 2.1588x; 1.0265x over previous
//
#include <hip/hip_runtime.h>
#include <math.h>

#define KSZ 5
#define TSX 16                // tile width (MFMA N = 16 pixels)
#define TSY 64                // tile height (each wave: 16 rows, 2 streams of 8)
#define HALO 3
#define FWX 22                // staged cols = TSX + 6
#define FH  70                // staged rows = TSY + 6
#define SCH 66                // sc rows = TSY + 2
#define PITCH 23              // uniform pitch for sf planes AND sc plane
#define SF_C (FH*PITCH)       // 1610 floats per flow channel
#define SC_BASE (2*SF_C)
#define SMF_TOT (SC_BASE + SCH*PITCH)

typedef __attribute__((ext_vector_type(8))) short short8_t;  // 8 bf16
typedef __attribute__((ext_vector_type(4))) float float4_t;

static __device__ __forceinline__ unsigned short f2bf(float f) {
    union { float f; unsigned int u; } v; v.f = f;
    return (unsigned short)((v.u + 0x7FFFu + ((v.u >> 16) & 1u)) >> 16);  // RNE
}
// truncating bf16 pack: low16 = hi16(a), high16 = hi16(b) — ONE v_perm_b32
static __device__ __forceinline__ unsigned int pk2t(float a, float b) {
    union { float f; unsigned int u; } ua, ub; ua.f = a; ub.f = b;
    return __builtin_amdgcn_perm(ub.u, ua.u, 0x07060302u);
}

// GEMM2 output slot n -> (c, sel, idx); j = sel*15 + idx; valid: sel?idx<10:idx<15
static __device__ __forceinline__ void slot_decode(int n, int& c, int& sel, int& idx, bool& valid) {
    int g4c = (n >> 2) & 3;
    c = g4c >> 1; sel = g4c & 1;
    idx = ((n >> 4) << 2) + (n & 3);
    valid = sel ? (idx < 10) : (idx < 15);
}

// GEMM1 K-permutation: k-slot s -> original guidance k (c*9 + ky*3 + kx), -1 = zero
static __device__ __forceinline__ int kperm(int s) {
    int sg = s >> 3, sj = s & 7;
    if (sg < 3) return sg*9 + sj;     // plane sg, taps 0..7
    if (sj == 1) return 8;            // c0 tap 8
    if (sj == 2) return 17;           // c1 tap 8
    if (sj == 4) return 26;           // cons tap 8
    return -1;
}

// GEMM2 K-permutation: k-slot s -> h channel the owning lane already holds.
static __device__ __forceinline__ int kperm2(int s) {
    int g = s >> 3, j = s & 7;
    return (j < 4) ? (g*4 + j) : (16 + g*4 + (j - 4));
}

// ---- one-block pack kernel: weights/biases -> MFMA-fragment order in ws ----
__global__ __launch_bounds__(256)
void pack_kernel(const float* __restrict__ w1, const float* __restrict__ b1,
                 const float* __restrict__ w2, const float* __restrict__ b2,
                 unsigned short* __restrict__ wp, float* __restrict__ bp)
{
    const int tid = threadIdx.x;
    for (int i = tid; i < 6*64*8; i += 256) {
        int f = i >> 9, l = (i >> 3) & 63, j = i & 7;
        int m = l & 15, s = ((l >> 4) << 3) + j;
        float v;
        if (f < 2) {
            int k = kperm(s);
            v = (k >= 0) ? w1[(f*16 + m)*27 + k] : 0.f;
        } else {
            int n = (f - 2)*16 + m;
            int c, sel, idx; bool valid;
            slot_decode(n, c, sel, idx, valid);
            v = valid ? w2[(c*25 + sel*15 + idx)*32 + kperm2(s)] : 0.f;
        }
        wp[i] = f2bf(v);
    }
    for (int i = tid; i < 6*64*4; i += 256) {
        int f = i >> 8, l = (i >> 2) & 63, r = i & 3, g4 = l >> 4;
        float v;
        if (f < 2) v = b1[f*16 + g4*4 + r];
        else {
            int n = (f - 2)*16 + g4*4 + r;
            int c, sel, idx; bool valid;
            slot_decode(n, c, sel, idx, valid);
            v = valid ? b2[c*25 + sel*15 + idx] : 0.f;
        }
        bp[i] = v;
    }
}

__global__ __launch_bounds__(256, 4)   // LDS caps at 4 blocks/CU anyway; allow 128 VGPR
void refine_kernel(const float* __restrict__ flow,
                   const unsigned short* __restrict__ wp,
                   const float* __restrict__ bp,
                   float* __restrict__ out, int H, int W)
{
    __shared__ float smf[SMF_TOT];                 // sf[2][70][23] | sc[66][23]
    __shared__ __align__(16) float4_t rs[FH*18];   // horizontal 5-tap sums

    const int tid = threadIdx.x;
    const int x0 = blockIdx.x * TSX;
    const int y0 = blockIdx.y * TSY;
    const int b  = blockIdx.z;

    const int lane = tid & 63;
    const int wave = tid >> 6;
    const int col  = lane & 15;
    const int g4   = lane >> 4;

    // ---- fragment loads from pre-packed ws ----
    short8_t w1A[2], w2A[4];
    float4_t cb1[2], cb2[4];
    #pragma unroll
    for (int nt = 0; nt < 2; ++nt) {
        w1A[nt] = *(const short8_t*)&wp[(nt*64 + lane)*8];
        cb1[nt] = *(const float4_t*)&bp[(nt*64 + lane)*4];
    }
    #pragma unroll
    for (int nt = 0; nt < 4; ++nt) {
        w2A[nt] = *(const short8_t*)&wp[((2+nt)*64 + lane)*8];
        cb2[nt] = *(const float4_t*)&bp[((2+nt)*64 + lane)*4];
    }

    // ---- phase 0: stage flow tile + halo; interior fast path ----
    {
        const float* srcb = flow + (size_t)(b*2) * H * W;
        if (x0 >= HALO && x0 + TSX + HALO <= W && y0 >= HALO && y0 + TSY + HALO <= H) {
            const float* s = srcb + (size_t)(y0 - HALO) * W + (x0 - HALO);
            for (int i = tid; i < 2*FH*FWX; i += 256) {
                int c = 0, r = i;
                if (r >= FH*FWX) { c = 1; r -= FH*FWX; }
                int ly = r / FWX, lx = r - ly*FWX;
                smf[c*SF_C + ly*PITCH + lx] = s[(size_t)c*H*W + ly*W + lx];
            }
        } else {
            for (int i = tid; i < 2*FH*FWX; i += 256) {
                int c = 0, r = i;
                if (r >= FH*FWX) { c = 1; r -= FH*FWX; }
                int ly = r / FWX, lx = r - ly*FWX;
                int gy = y0 - HALO + ly, gx = x0 - HALO + lx;
                float v = 0.f;
                if (gy >= 0 && gy < H && gx >= 0 && gx < W)
                    v = srcb[(size_t)c*H*W + (size_t)gy*W + gx];
                smf[c*SF_C + ly*PITCH + lx] = v;
            }
        }
    }
    __syncthreads();

    // ---- phase 1a: horizontal 5-tap sums (s, sum v^2), 2 adjacent outputs ----
    for (int i = tid; i < FH*9; i += 256) {        // 630 units
        int y = i / 9, xp = (i - y*9) * 2;
        const float* r0 = &smf[y*PITCH + xp];
        const float* r1 = &smf[SF_C + y*PITCH + xp];
        float a0=r0[0], a1=r0[1], a2=r0[2], a3=r0[3], a4=r0[4], a5=r0[5];
        float c0=r1[0], c1=r1[1], c2=r1[2], c3=r1[3], c4=r1[4], c5=r1[5];
        float sA = ((a0+a1)+(a2+a3))+a4;
        float qA = fmaf(a4,a4, fmaf(a3,a3, fmaf(a2,a2, fmaf(a1,a1, a0*a0))));
        float sB = ((c0+c1)+(c2+c3))+c4;
        float qB = fmaf(c4,c4, fmaf(c3,c3, fmaf(c2,c2, fmaf(c1,c1, c0*c0))));
        float sA1 = sA + a5 - a0;
        float qA1 = fmaf(-a0, a0, fmaf(a5, a5, qA));
        float sB1 = sB + c5 - c0;
        float qB1 = fmaf(-c0, c0, fmaf(c5, c5, qB));
        rs[y*18 + xp]     = (float4_t){sA,  qA,  sB,  qB };
        rs[y*18 + xp + 1] = (float4_t){sA1, qA1, sB1, qB1};
    }
    __syncthreads();

    // ---- phase 1b: vertical 5-row sums, 2 vertically-adjacent outputs/thread ----
    for (int i = tid; i < (SCH/2)*18; i += 256) {  // 594 units
        int u = i / 18, px = i - u*18;
        int py0 = u*2;
        int gx = x0 - 1 + px;
        int gy0 = y0 - 1 + py0;
        const float4_t* rp = rs + py0*18 + px;
        float4_t r0 = rp[0], r1 = rp[18], r2 = rp[2*18], r3 = rp[3*18],
                 r4 = rp[4*18], r5 = rp[5*18];
        float4_t mid = (r1 + r2) + (r3 + r4);
        float4_t acc0 = mid + r0;
        float4_t acc1 = mid + r5;
        float cons0 = 0.f, cons1 = 0.f;
        bool okx = (gx >= 0) && (gx < W);
        if (okx && gy0 >= 0 && gy0 < H) {
            float v0 = (acc0.y - acc0.x*acc0.x*(1.f/25.f)) * (1.f/24.f);
            float v1 = (acc0.w - acc0.z*acc0.z*(1.f/25.f)) * (1.f/24.f);
            cons0 = __expf(-sqrtf(v0*v0 + v1*v1));
        }
        if (okx && gy0+1 >= 0 && gy0+1 < H) {
            float v0 = (acc1.y - acc1.x*acc1.x*(1.f/25.f)) * (1.f/24.f);
            float v1 = (acc1.w - acc1.z*acc1.z*(1.f/25.f)) * (1.f/24.f);
            cons1 = __expf(-sqrtf(v0*v0 + v1*v1));
        }
        smf[SC_BASE + py0*PITCH + px]       = cons0;
        smf[SC_BASE + (py0+1)*PITCH + px]   = cons1;
    }
    __syncthreads();

    // ---- main: two independent row-streams per wave (ILP) ----
    const int sel = g4 & 1, pc = g4 >> 1;
    const int tyA = wave*16, tyB = wave*16 + 8;

    // guidance bases per stream (uniform immediates {0,1},{2,23},{24,25},{46,47})
    int gA0, gA1, gA2, gA3, gB0, gB1, gB2, gB3;
    {
        int p0 = 0*SF_C + 2*PITCH + (col + 2);
        int p1 = 1*SF_C + 2*PITCH + (col + 2);
        int p2 = SC_BASE + col;
        int q0, q1, q2, q3;
        if (g4 == 0)      { q0 = q1 = q2 = q3 = p0; }
        else if (g4 == 1) { q0 = q1 = q2 = q3 = p1; }
        else if (g4 == 2) { q0 = q1 = q2 = q3 = p2; }
        else { q0 = p0 + 47; q1 = p1 + 46; q2 = p2 + 24; q3 = p0; }
        gA0 = q0 + tyA*((g4==2) ? PITCH : PITCH); // pitch uniform = PITCH
        gA0 = q0 + tyA*PITCH; gA1 = q1 + tyA*PITCH; gA2 = q2 + tyA*PITCH; gA3 = q3 + tyA*PITCH;
        gB0 = q0 + tyB*PITCH; gB1 = q1 + tyB*PITCH; gB2 = q2 + tyB*PITCH; gB3 = q3 + tyB*PITCH;
    }

    // patch pipelines per stream
    const int pbase = pc*SF_C + sel*(3*PITCH) + PITCH + 1 + col;
    int pbA = pbase + tyA*PITCH, pbB = pbase + tyB*PITCH;
    float pvA[15], pvB[15];
    #pragma unroll
    for (int i = 0; i < 15; ++i) pvA[i] = smf[pbA + (i/5)*PITCH + (i%5)];
    #pragma unroll
    for (int i = 0; i < 15; ++i) pvB[i] = smf[pbB + (i/5)*PITCH + (i%5)];

    #pragma unroll
    for (int mt = 0; mt < 8; ++mt) {
        // ---------- stream A ----------
        float sA;
        {
            float ga = smf[gA0 + 0],  gb_ = smf[gA0 + 1];
            float gc = smf[gA1 + 2],  gd  = smf[gA1 + 23];
            float ge = smf[gA2 + 24], gf  = smf[gA2 + 25];
            float gg = smf[gA3 + 46], gh  = smf[gA3 + 47];
            union { unsigned int u[4]; short8_t s; } gu;
            gu.u[0] = pk2t(ga, gb_); gu.u[1] = pk2t(gc, gd);
            gu.u[2] = pk2t(ge, gf);  gu.u[3] = pk2t(gg, gh);
            gA0 += PITCH; gA1 += PITCH; gA2 += PITCH; gA3 += PITCH;
            float4_t h0 = __builtin_amdgcn_mfma_f32_16x16x32_bf16(w1A[0], gu.s, cb1[0], 0, 0, 0);
            float4_t h1 = __builtin_amdgcn_mfma_f32_16x16x32_bf16(w1A[1], gu.s, cb1[1], 0, 0, 0);
            union { unsigned int u[4]; short8_t s; } hu;
            hu.u[0] = pk2t(fmaxf(h0[0],0.f), fmaxf(h0[1],0.f));
            hu.u[1] = pk2t(fmaxf(h0[2],0.f), fmaxf(h0[3],0.f));
            hu.u[2] = pk2t(fmaxf(h1[0],0.f), fmaxf(h1[1],0.f));
            hu.u[3] = pk2t(fmaxf(h1[2],0.f), fmaxf(h1[3],0.f));
            float4_t ka[4];
            #pragma unroll
            for (int nt = 0; nt < 4; ++nt)
                ka[nt] = __builtin_amdgcn_mfma_f32_16x16x32_bf16(w2A[nt], hu.s, cb2[nt], 0, 0, 0);
            float s = 0.f;
            #pragma unroll
            for (int i = 0; i < 15; ++i)
                s = fmaf(ka[i >> 2][i & 3], pvA[i], s);
            if (mt < 7) {
                #pragma unroll
                for (int i = 0; i < 10; ++i) pvA[i] = pvA[i + 5];
                pbA += PITCH;
                #pragma unroll
                for (int i = 10; i < 15; ++i) pvA[i] = smf[pbA + (i/5)*PITCH + (i%5)];
            }
            sA = s;
        }
        // ---------- stream B ----------
        float sB;
        {
            float ga = smf[gB0 + 0],  gb_ = smf[gB0 + 1];
            float gc = smf[gB1 + 2],  gd  = smf[gB1 + 23];
            float ge = smf[gB2 + 24], gf  = smf[gB2 + 25];
            float gg = smf[gB3 + 46], gh  = smf[gB3 + 47];
            union { unsigned int u[4]; short8_t s; } gu;
            gu.u[0] = pk2t(ga, gb_); gu.u[1] = pk2t(gc, gd);
            gu.u[2] = pk2t(ge, gf);  gu.u[3] = pk2t(gg, gh);
            gB0 += PITCH; gB1 += PITCH; gB2 += PITCH; gB3 += PITCH;
            float4_t h0 = __builtin_amdgcn_mfma_f32_16x16x32_bf16(w1A[0], gu.s, cb1[0], 0, 0, 0);
            float4_t h1 = __builtin_amdgcn_mfma_f32_16x16x32_bf16(w1A[1], gu.s, cb1[1], 0, 0, 0);
            union { unsigned int u[4]; short8_t s; } hu;
            hu.u[0] = pk2t(fmaxf(h0[0],0.f), fmaxf(h0[1],0.f));
            hu.u[1] = pk2t(fmaxf(h0[2],0.f), fmaxf(h0[3],0.f));
            hu.u[2] = pk2t(fmaxf(h1[0],0.f), fmaxf(h1[1],0.f));
            hu.u[3] = pk2t(fmaxf(h1[2],0.f), fmaxf(h1[3],0.f));
            float4_t ka[4];
            #pragma unroll
            for (int nt = 0; nt < 4; ++nt)
                ka[nt] = __builtin_amdgcn_mfma_f32_16x16x32_bf16(w2A[nt], hu.s, cb2[nt], 0, 0, 0);
            float s = 0.f;
            #pragma unroll
            for (int i = 0; i < 15; ++i)
                s = fmaf(ka[i >> 2][i & 3], pvB[i], s);
            if (mt < 7) {
                #pragma unroll
                for (int i = 0; i < 10; ++i) pvB[i] = pvB[i + 5];
                pbB += PITCH;
                #pragma unroll
                for (int i = 10; i < 15; ++i) pvB[i] = smf[pbB + (i/5)*PITCH + (i%5)];
            }
            sB = s;
        }

        // combine sel partitions: lanes g4 0<->1 (c=0), 2<->3 (c=1)
        sA += __shfl_xor(sA, 16);
        sB += __shfl_xor(sB, 16);

        if (sel == 0) {
            int x = x0 + col;
            size_t base = ((size_t)(b*2 + pc) * H) * W + x;
            out[base + (size_t)(y0 + tyA + mt) * W] = sA;
            out[base + (size_t)(y0 + tyB + mt) * W] = sB;
        }
    }
}

extern "C" void kernel_launch(void* const* d_in, const int* in_sizes, int n_in,
                              void* d_out, int out_size, void* d_ws, size_t ws_size,
                              hipStream_t stream) {
    const float* flow = (const float*)d_in[0];
    const float* w1   = (const float*)d_in[1];
    const float* b1   = (const float*)d_in[2];
    const float* w2   = (const float*)d_in[3];
    const float* b2   = (const float*)d_in[4];
    float* out = (float*)d_out;

    unsigned short* wp = (unsigned short*)d_ws;                 // 6*64*8 ushort = 6 KB
    float* bp = (float*)((char*)d_ws + 8192);                   // 6*64*4 float = 6 KB

    const int H = 1024, W = 1024;
    const int B = in_sizes[0] / (2 * H * W);

    pack_kernel<<<1, 256, 0, stream>>>(w1, b1, w2, b2, wp, bp);
    dim3 grid(W / TSX, H / TSY, B);
    refine_kernel<<<grid, dim3(256), 0, stream>>>(flow, wp, bp, out, H, W);
}